// Round 2
// baseline (2568.472 us; speedup 1.0000x reference)
//
#include <hip/hip_runtime.h>
#include <math.h>

#define N_NODES 65536
#define N_EDGES 524288
#define HDIM 256
#define NLAYERS 9
#define NCLUST 4096
#define HQ 64
#define INCF 11

__device__ __forceinline__ float gelu_exact(float v) {
    return 0.5f * v * (1.0f + erff(v * 0.70710678118654752440f));
}

// ---------------- encoder: wave per node ----------------
__global__ __launch_bounds__(256) void encoder_kernel(
    const float* __restrict__ x_geo, const int* __restrict__ id_index,
    const float* __restrict__ id_emb,
    const float* __restrict__ w1, const float* __restrict__ b1,
    const float* __restrict__ w2, const float* __restrict__ b2,
    const float* __restrict__ w3, const float* __restrict__ b3,
    const float* __restrict__ sw, const float* __restrict__ sb,
    float* __restrict__ xout)
{
    int gtid = blockIdx.x * blockDim.x + threadIdx.x;
    int node = gtid >> 6;
    int lane = threadIdx.x & 63;
    if (node >= N_NODES) return;

    float nf[INCF];
    nf[0] = x_geo[node * 3 + 0];
    nf[1] = x_geo[node * 3 + 1];
    nf[2] = x_geo[node * 3 + 2];
    int idv = id_index[node];
#pragma unroll
    for (int k = 0; k < 8; ++k) nf[3 + k] = id_emb[idv * 8 + k];

    // h1 = gelu(node @ w1 + b1)   [64], lane t owns h1[t]
    float acc = b1[lane];
#pragma unroll
    for (int k = 0; k < INCF; ++k) acc += nf[k] * w1[k * HQ + lane];
    float h1 = gelu_exact(acc);

    // h2 = gelu(h1 @ w2 + b2)
    acc = b2[lane];
    for (int k = 0; k < HQ; ++k) acc += __shfl(h1, k) * w2[k * HQ + lane];
    float h2 = gelu_exact(acc);

    // x = gelu(node @ sw + sb + h2 @ w3 + b3)   [256]
    float a4[4];
#pragma unroll
    for (int j0 = 0; j0 < 4; ++j0) {
        int j = j0 * 64 + lane;
        a4[j0] = b3[j] + sb[j];
    }
    for (int k = 0; k < HQ; ++k) {
        float hk = __shfl(h2, k);
#pragma unroll
        for (int j0 = 0; j0 < 4; ++j0) a4[j0] += hk * w3[k * HDIM + j0 * 64 + lane];
    }
#pragma unroll
    for (int k = 0; k < INCF; ++k) {
        float nk = nf[k];
#pragma unroll
        for (int j0 = 0; j0 < 4; ++j0) a4[j0] += nk * sw[k * HDIM + j0 * 64 + lane];
    }
#pragma unroll
    for (int j0 = 0; j0 < 4; ++j0)
        xout[node * HDIM + j0 * 64 + lane] = gelu_exact(a4[j0]);
}

// ---------------- degree / CSR build ----------------
__global__ void count_kernel(const int* __restrict__ dst, int* __restrict__ degi) {
    int e = blockIdx.x * blockDim.x + threadIdx.x;
    if (e < N_EDGES) atomicAdd(&degi[dst[e]], 1);
}

__global__ void dis_kernel(const int* __restrict__ degi, float* __restrict__ dis) {
    int n = blockIdx.x * blockDim.x + threadIdx.x;
    if (n < N_NODES) dis[n] = rsqrtf((float)degi[n] + 1.0f);
}

__global__ __launch_bounds__(1024) void scan_kernel(const int* __restrict__ degi,
                                                    int* __restrict__ off) {
    __shared__ int part[1024];
    int t = threadIdx.x;
    int base = t * 64;
    int s = 0;
    for (int j = 0; j < 64; ++j) s += degi[base + j];
    part[t] = s;
    __syncthreads();
    for (int d = 1; d < 1024; d <<= 1) {
        int v = (t >= d) ? part[t - d] : 0;
        __syncthreads();
        part[t] += v;
        __syncthreads();
    }
    int run = (t == 0) ? 0 : part[t - 1];
    for (int j = 0; j < 64; ++j) {
        off[base + j] = run;
        run += degi[base + j];
    }
    if (t == 1023) off[N_NODES] = run;
}

__global__ void fill_kernel(const int* __restrict__ src, const int* __restrict__ dst,
                            const int* __restrict__ off, int* __restrict__ cursor,
                            int* __restrict__ csr_src) {
    int e = blockIdx.x * blockDim.x + threadIdx.x;
    if (e >= N_EDGES) return;
    int d = dst[e];
    int pos = off[d] + atomicAdd(&cursor[d], 1);
    csr_src[pos] = src[e];
}

// ---------------- fp32 tiled GEMM: hi = x @ W  (N x 256 @ 256 x 256) ----------------
__global__ __launch_bounds__(256) void gemm_kernel(const float* __restrict__ A,
                                                   const float* __restrict__ B,
                                                   float* __restrict__ C_) {
    __shared__ float As[16][65];  // transposed, padded
    __shared__ float Bs[16][64];
    int tid = threadIdx.x;
    int bm = blockIdx.y, bn = blockIdx.x;
    int tx = tid & 15, ty = tid >> 4;
    int ar = tid >> 2, ac = (tid & 3) * 4;
    int br = tid >> 4, bc = (tid & 15) * 4;
    float acc[4][4] = {};
    for (int k0 = 0; k0 < HDIM; k0 += 16) {
        float4 av = *(const float4*)(A + (size_t)(bm * 64 + ar) * HDIM + k0 + ac);
        float4 bv = *(const float4*)(B + (size_t)(k0 + br) * HDIM + bn * 64 + bc);
        __syncthreads();
        As[ac + 0][ar] = av.x;
        As[ac + 1][ar] = av.y;
        As[ac + 2][ar] = av.z;
        As[ac + 3][ar] = av.w;
        *(float4*)&Bs[br][bc] = bv;
        __syncthreads();
#pragma unroll
        for (int k = 0; k < 16; ++k) {
            float a0 = As[k][ty * 4 + 0], a1 = As[k][ty * 4 + 1];
            float a2 = As[k][ty * 4 + 2], a3 = As[k][ty * 4 + 3];
            float b0 = Bs[k][tx * 4 + 0], b1 = Bs[k][tx * 4 + 1];
            float b2 = Bs[k][tx * 4 + 2], b3 = Bs[k][tx * 4 + 3];
            acc[0][0] += a0 * b0; acc[0][1] += a0 * b1; acc[0][2] += a0 * b2; acc[0][3] += a0 * b3;
            acc[1][0] += a1 * b0; acc[1][1] += a1 * b1; acc[1][2] += a1 * b2; acc[1][3] += a1 * b3;
            acc[2][0] += a2 * b0; acc[2][1] += a2 * b1; acc[2][2] += a2 * b2; acc[2][3] += a2 * b3;
            acc[3][0] += a3 * b0; acc[3][1] += a3 * b1; acc[3][2] += a3 * b2; acc[3][3] += a3 * b3;
        }
    }
#pragma unroll
    for (int i = 0; i < 4; ++i) {
        float4 v = make_float4(acc[i][0], acc[i][1], acc[i][2], acc[i][3]);
        *(float4*)(C_ + (size_t)(bm * 64 + ty * 4 + i) * HDIM + bn * 64 + tx * 4) = v;
    }
}

// ---------------- fused aggregate + self + bias + LN + relu (+residual) ----------------
__global__ __launch_bounds__(256) void agg_ln_kernel(
    const float* __restrict__ hi, const float* __restrict__ dis,
    const int* __restrict__ off, const int* __restrict__ csr_src,
    const float* __restrict__ bias, const float* __restrict__ g,
    const float* __restrict__ bln, float* __restrict__ x, int addResidual)
{
    int gtid = blockIdx.x * blockDim.x + threadIdx.x;
    int n = gtid >> 6;
    int lane = threadIdx.x & 63;
    if (n >= N_NODES) return;
    float dn = dis[n];
    float4 acc = make_float4(0.f, 0.f, 0.f, 0.f);
    int p0 = off[n], p1 = off[n + 1];
    for (int p = p0; p < p1; ++p) {
        int s = csr_src[p];
        float w = dis[s] * dn;
        float4 v = *(const float4*)(hi + (size_t)s * HDIM + lane * 4);
        acc.x += v.x * w; acc.y += v.y * w; acc.z += v.z * w; acc.w += v.w * w;
    }
    {
        float w = dn * dn;
        float4 v = *(const float4*)(hi + (size_t)n * HDIM + lane * 4);
        acc.x += v.x * w; acc.y += v.y * w; acc.z += v.z * w; acc.w += v.w * w;
    }
    {
        float4 bv = *(const float4*)(bias + lane * 4);
        acc.x += bv.x; acc.y += bv.y; acc.z += bv.z; acc.w += bv.w;
    }
    float s1 = acc.x + acc.y + acc.z + acc.w;
    float s2 = acc.x * acc.x + acc.y * acc.y + acc.z * acc.z + acc.w * acc.w;
#pragma unroll
    for (int m = 1; m < 64; m <<= 1) {
        s1 += __shfl_xor(s1, m);
        s2 += __shfl_xor(s2, m);
    }
    float mu = s1 * (1.0f / 256.0f);
    float var = s2 * (1.0f / 256.0f) - mu * mu;
    float inv = rsqrtf(var + 1e-5f);
    float4 gv = *(const float4*)(g + lane * 4);
    float4 bb = *(const float4*)(bln + lane * 4);
    float4 res;
    res.x = fmaxf((acc.x - mu) * inv * gv.x + bb.x, 0.0f);
    res.y = fmaxf((acc.y - mu) * inv * gv.y + bb.y, 0.0f);
    res.z = fmaxf((acc.z - mu) * inv * gv.z + bb.z, 0.0f);
    res.w = fmaxf((acc.w - mu) * inv * gv.w + bb.w, 0.0f);
    if (addResidual) {
        float4 o = *(const float4*)(x + (size_t)n * HDIM + lane * 4);
        res.x += o.x; res.y += o.y; res.z += o.z; res.w += o.w;
    }
    *(float4*)(x + (size_t)n * HDIM + lane * 4) = res;
}

// ---------------- pooling + per-feature L2 normalize ----------------
__global__ __launch_bounds__(256) void pool_kernel(const float* __restrict__ x,
                                                   const int* __restrict__ cluster,
                                                   float* __restrict__ pooled,
                                                   float* __restrict__ cnt) {
    int gtid = blockIdx.x * blockDim.x + threadIdx.x;
    int n = gtid >> 6;
    int lane = threadIdx.x & 63;
    if (n >= N_NODES) return;
    int c = cluster[n];
    if (lane == 0) atomicAdd(&cnt[c], 1.0f);
    float4 v = *(const float4*)(x + (size_t)n * HDIM + lane * 4);
    float* p = &pooled[(size_t)c * HDIM + lane * 4];
    atomicAdd(p + 0, v.x);
    atomicAdd(p + 1, v.y);
    atomicAdd(p + 2, v.z);
    atomicAdd(p + 3, v.w);
}

__global__ __launch_bounds__(256) void colsq_kernel(float* __restrict__ pooled,
                                                    const float* __restrict__ cnt,
                                                    float* __restrict__ colsq) {
    int h = threadIdx.x;
    int c0 = blockIdx.x * 16;
    float sq = 0.f;
    for (int cc = 0; cc < 16; ++cc) {
        int c = c0 + cc;
        float ct = fmaxf(cnt[c], 1.0f);
        float v = pooled[(size_t)c * HDIM + h] / ct;
        pooled[(size_t)c * HDIM + h] = v;
        sq += v * v;
    }
    atomicAdd(&colsq[h], sq);
}

__global__ __launch_bounds__(256) void final_kernel(const float* __restrict__ pooled,
                                                    const float* __restrict__ colsq,
                                                    float* __restrict__ out) {
    int i = blockIdx.x * blockDim.x + threadIdx.x;
    if (i >= NCLUST * HDIM) return;
    int h = i & (HDIM - 1);
    float nrm = fmaxf(sqrtf(colsq[h]), 1e-6f);
    out[i] = pooled[i] / nrm;
}

extern "C" void kernel_launch(void* const* d_in, const int* in_sizes, int n_in,
                              void* d_out, int out_size, void* d_ws, size_t ws_size,
                              hipStream_t stream) {
    const float* x_geo   = (const float*)d_in[0];
    const int*   id_index = (const int*)d_in[1];
    const int*   edge_index = (const int*)d_in[2];
    const int*   cluster = (const int*)d_in[3];
    const float* id_emb  = (const float*)d_in[4];
    const float* enc_w1  = (const float*)d_in[5];
    const float* enc_b1  = (const float*)d_in[6];
    const float* enc_w2  = (const float*)d_in[7];
    const float* enc_b2  = (const float*)d_in[8];
    const float* enc_w3  = (const float*)d_in[9];
    const float* enc_b3  = (const float*)d_in[10];
    const float* skip_w  = (const float*)d_in[11];
    const float* skip_b  = (const float*)d_in[12];
    const float* gcn_w   = (const float*)d_in[13];
    const float* gcn_b   = (const float*)d_in[14];
    const float* ln_g    = (const float*)d_in[15];
    const float* ln_b    = (const float*)d_in[16];
    float* out = (float*)d_out;

    char* ws = (char*)d_ws;
    size_t o = 0;
    auto alloc = [&](size_t bytes) {
        char* p = ws + o;
        o += (bytes + 255) & ~(size_t)255;
        return p;
    };
    float* x      = (float*)alloc((size_t)N_NODES * HDIM * 4);
    float* hi     = (float*)alloc((size_t)N_NODES * HDIM * 4);
    int*   degi   = (int*)alloc((size_t)N_NODES * 4);
    float* dis    = (float*)alloc((size_t)N_NODES * 4);
    int*   off    = (int*)alloc((size_t)(N_NODES + 1) * 4);
    int*   cursor = (int*)alloc((size_t)N_NODES * 4);
    int*   csr_src = (int*)alloc((size_t)N_EDGES * 4);
    float* pooled = (float*)alloc((size_t)NCLUST * HDIM * 4);
    float* cnt    = (float*)alloc((size_t)NCLUST * 4);
    float* colsq  = (float*)alloc((size_t)256 * 4);

    const int* esrc = edge_index;
    const int* edst = edge_index + N_EDGES;

    hipMemsetAsync(degi, 0, (size_t)N_NODES * 4, stream);
    hipMemsetAsync(cursor, 0, (size_t)N_NODES * 4, stream);

    encoder_kernel<<<N_NODES / 4, 256, 0, stream>>>(
        x_geo, id_index, id_emb, enc_w1, enc_b1, enc_w2, enc_b2, enc_w3, enc_b3,
        skip_w, skip_b, x);

    count_kernel<<<N_EDGES / 256, 256, 0, stream>>>(edst, degi);
    dis_kernel<<<N_NODES / 256, 256, 0, stream>>>(degi, dis);
    scan_kernel<<<1, 1024, 0, stream>>>(degi, off);
    fill_kernel<<<N_EDGES / 256, 256, 0, stream>>>(esrc, edst, off, cursor, csr_src);

    for (int i = 0; i < NLAYERS; ++i) {
        gemm_kernel<<<dim3(HDIM / 64, N_NODES / 64), 256, 0, stream>>>(
            x, gcn_w + (size_t)i * HDIM * HDIM, hi);
        agg_ln_kernel<<<N_NODES / 4, 256, 0, stream>>>(
            hi, dis, off, csr_src, gcn_b + (size_t)i * HDIM,
            ln_g + (size_t)i * HDIM, ln_b + (size_t)i * HDIM, x, (i == 0) ? 1 : 0);
    }

    hipMemsetAsync(pooled, 0, (size_t)NCLUST * HDIM * 4, stream);
    hipMemsetAsync(cnt, 0, (size_t)NCLUST * 4, stream);
    hipMemsetAsync(colsq, 0, (size_t)256 * 4, stream);
    pool_kernel<<<N_NODES / 4, 256, 0, stream>>>(x, cluster, pooled, cnt);
    colsq_kernel<<<NCLUST / 16, 256, 0, stream>>>(pooled, cnt, colsq);
    final_kernel<<<NCLUST * HDIM / 256, 256, 0, stream>>>(pooled, colsq, out);
}

// Round 5
// 2209.028 us; speedup vs baseline: 1.1627x; 1.1627x over previous
//
#include <hip/hip_runtime.h>
#include <math.h>

#define N_NODES 65536
#define N_EDGES 524288
#define HDIM 256
#define NLAYERS 9
#define NCLUST 4096
#define HQ 64
#define INCF 11

typedef __attribute__((ext_vector_type(8))) short short8v;
typedef __attribute__((ext_vector_type(4))) float f32x4;

__device__ __forceinline__ float gelu_exact(float v) {
    return 0.5f * v * (1.0f + erff(v * 0.70710678118654752440f));
}

__device__ __forceinline__ unsigned short f2bf(float f) {
    union { float f; unsigned u; } a; a.f = f;
    unsigned r = a.u + 0x7FFFu + ((a.u >> 16) & 1u);  // round-nearest-even
    return (unsigned short)(r >> 16);
}

__device__ __forceinline__ float bf2f(unsigned short h) {
    union { unsigned u; float f; } a; a.u = ((unsigned)h) << 16;
    return a.f;
}

// split v into hi+lo bf16 (carries ~16 mantissa bits total)
__device__ __forceinline__ void split_bf(float v, unsigned short& h, unsigned short& l) {
    h = f2bf(v);
    l = f2bf(v - bf2f(h));
}

// ---------------- encoder: wave per node (writes x fp32 + xb hi/lo bf16) ----------------
__global__ __launch_bounds__(256) void encoder_kernel(
    const float* __restrict__ x_geo, const int* __restrict__ id_index,
    const float* __restrict__ id_emb,
    const float* __restrict__ w1, const float* __restrict__ b1,
    const float* __restrict__ w2, const float* __restrict__ b2,
    const float* __restrict__ w3, const float* __restrict__ b3,
    const float* __restrict__ sw, const float* __restrict__ sb,
    float* __restrict__ xout, unsigned short* __restrict__ xh,
    unsigned short* __restrict__ xl)
{
    int gtid = blockIdx.x * blockDim.x + threadIdx.x;
    int node = gtid >> 6;
    int lane = threadIdx.x & 63;
    if (node >= N_NODES) return;

    float nf[INCF];
    nf[0] = x_geo[node * 3 + 0];
    nf[1] = x_geo[node * 3 + 1];
    nf[2] = x_geo[node * 3 + 2];
    int idv = id_index[node];
#pragma unroll
    for (int k = 0; k < 8; ++k) nf[3 + k] = id_emb[idv * 8 + k];

    float acc = b1[lane];
#pragma unroll
    for (int k = 0; k < INCF; ++k) acc += nf[k] * w1[k * HQ + lane];
    float h1 = gelu_exact(acc);

    acc = b2[lane];
    for (int k = 0; k < HQ; ++k) acc += __shfl(h1, k) * w2[k * HQ + lane];
    float h2 = gelu_exact(acc);

    float a4[4];
#pragma unroll
    for (int j0 = 0; j0 < 4; ++j0) {
        int j = j0 * 64 + lane;
        a4[j0] = b3[j] + sb[j];
    }
    for (int k = 0; k < HQ; ++k) {
        float hk = __shfl(h2, k);
#pragma unroll
        for (int j0 = 0; j0 < 4; ++j0) a4[j0] += hk * w3[k * HDIM + j0 * 64 + lane];
    }
#pragma unroll
    for (int k = 0; k < INCF; ++k) {
        float nk = nf[k];
#pragma unroll
        for (int j0 = 0; j0 < 4; ++j0) a4[j0] += nk * sw[k * HDIM + j0 * 64 + lane];
    }
#pragma unroll
    for (int j0 = 0; j0 < 4; ++j0) {
        float v = gelu_exact(a4[j0]);
        xout[node * HDIM + j0 * 64 + lane] = v;
        unsigned short h, l;
        split_bf(v, h, l);
        xh[node * HDIM + j0 * 64 + lane] = h;
        xl[node * HDIM + j0 * 64 + lane] = l;
    }
}

// ---------------- degree / edge-CSR build ----------------
__global__ void count_kernel(const int* __restrict__ dst, int* __restrict__ degi) {
    int e = blockIdx.x * blockDim.x + threadIdx.x;
    if (e < N_EDGES) atomicAdd(&degi[dst[e]], 1);
}

__global__ void dis_kernel(const int* __restrict__ degi, float* __restrict__ dis) {
    int n = blockIdx.x * blockDim.x + threadIdx.x;
    if (n < N_NODES) dis[n] = rsqrtf((float)degi[n] + 1.0f);
}

__global__ __launch_bounds__(1024) void scan_kernel(const int* __restrict__ degi,
                                                    int* __restrict__ off) {
    __shared__ int part[1024];
    int t = threadIdx.x;
    int base = t * 64;
    int s = 0;
    for (int j = 0; j < 64; ++j) s += degi[base + j];
    part[t] = s;
    __syncthreads();
    for (int d = 1; d < 1024; d <<= 1) {
        int v = (t >= d) ? part[t - d] : 0;
        __syncthreads();
        part[t] += v;
        __syncthreads();
    }
    int run = (t == 0) ? 0 : part[t - 1];
    for (int j = 0; j < 64; ++j) {
        off[base + j] = run;
        run += degi[base + j];
    }
    if (t == 1023) off[N_NODES] = run;
}

__global__ void fill_kernel(const int* __restrict__ src, const int* __restrict__ dst,
                            const int* __restrict__ off, int* __restrict__ cursor,
                            int* __restrict__ csr_src) {
    int e = blockIdx.x * blockDim.x + threadIdx.x;
    if (e >= N_EDGES) return;
    int d = dst[e];
    int pos = off[d] + atomicAdd(&cursor[d], 1);
    csr_src[pos] = src[e];
}

// ---------------- weight transpose + bf16 hi/lo: wt[l][n][k] = w[l][k][n] ----------------
__global__ __launch_bounds__(256) void wtrans_kernel(const float* __restrict__ w,
                                                     unsigned short* __restrict__ wth,
                                                     unsigned short* __restrict__ wtl_) {
    __shared__ float t[32][257];
    int l = blockIdx.y, kb = blockIdx.x;  // 8 kb blocks of 32 rows
    const float* wl = w + (size_t)l * HDIM * HDIM + (size_t)kb * 32 * HDIM;
#pragma unroll
    for (int it = 0; it < 32; ++it) {
        int idx = it * 256 + threadIdx.x;
        t[idx >> 8][idx & 255] = wl[idx];
    }
    __syncthreads();
    unsigned short* wh = wth + (size_t)l * HDIM * HDIM + kb * 32;
    unsigned short* wl2 = wtl_ + (size_t)l * HDIM * HDIM + kb * 32;
    int k = threadIdx.x & 31, n0 = threadIdx.x >> 5;
#pragma unroll
    for (int it = 0; it < 32; ++it) {
        int n = it * 8 + n0;
        unsigned short h, lo;
        split_bf(t[k][n], h, lo);
        wh[(size_t)n * HDIM + k] = h;
        wl2[(size_t)n * HDIM + k] = lo;
    }
}

// ---------------- bf16x3 MFMA GEMM: hi = x @ W with hi/lo error compensation ----------------
// 128x128 tile, BK=32, 4 waves (2x2 of 64x64), 16x16x32 MFMA.
// acc += Ah*Bh + Ah*Bl + Al*Bh  (lo*lo dropped, ~2^-18)
// LDS chunk swizzle sub^((row>>1)&3) keeps fragment ds_read_b128 ~2-way (free).
__global__ __launch_bounds__(256) void mfma_gemm_kernel(
    const unsigned short* __restrict__ Ah, const unsigned short* __restrict__ Al,
    const unsigned short* __restrict__ Bh, const unsigned short* __restrict__ Bl,
    float* __restrict__ C_)
{
    __shared__ unsigned short AsH[128 * 32];
    __shared__ unsigned short AsL[128 * 32];
    __shared__ unsigned short BsH[128 * 32];
    __shared__ unsigned short BsL[128 * 32];
    int tid = threadIdx.x;
    int w = tid >> 6, l = tid & 63;
    int bn = blockIdx.x, bm = blockIdx.y;
    int wm = w >> 1, wn = w & 1;
    int fr = l & 15, fs = l >> 4;

    f32x4 acc[4][4];
#pragma unroll
    for (int m = 0; m < 4; ++m)
#pragma unroll
        for (int n = 0; n < 4; ++n) acc[m][n] = (f32x4){0.f, 0.f, 0.f, 0.f};

    const size_t aoff = (size_t)(bm * 128) * HDIM;
    const size_t boff = (size_t)(bn * 128) * HDIM;

#pragma unroll
    for (int k0 = 0; k0 < HDIM; k0 += 32) {
        uint4 vah[2], val[2], vbh[2], vbl[2];
#pragma unroll
        for (int j = 0; j < 2; ++j) {
            int s = j * 256 + tid;
            int row = s >> 2, sub = s & 3;
            size_t g = (size_t)row * HDIM + k0 + sub * 8;
            vah[j] = *(const uint4*)(Ah + aoff + g);
            val[j] = *(const uint4*)(Al + aoff + g);
            vbh[j] = *(const uint4*)(Bh + boff + g);
            vbl[j] = *(const uint4*)(Bl + boff + g);
        }
        __syncthreads();
#pragma unroll
        for (int j = 0; j < 2; ++j) {
            int s = j * 256 + tid;
            int row = s >> 2, sub = s & 3;
            int cl = row * 4 + (sub ^ ((row >> 1) & 3));
            *(uint4*)&AsH[cl * 8] = vah[j];
            *(uint4*)&AsL[cl * 8] = val[j];
            *(uint4*)&BsH[cl * 8] = vbh[j];
            *(uint4*)&BsL[cl * 8] = vbl[j];
        }
        __syncthreads();

        short8v afh[4], afl[4], bfh[4], bfl[4];
#pragma unroll
        for (int m = 0; m < 4; ++m) {
            int row = wm * 64 + m * 16 + fr;
            int cl = row * 4 + (fs ^ ((row >> 1) & 3));
            afh[m] = *(const short8v*)&AsH[cl * 8];
            afl[m] = *(const short8v*)&AsL[cl * 8];
        }
#pragma unroll
        for (int n = 0; n < 4; ++n) {
            int row = wn * 64 + n * 16 + fr;
            int cl = row * 4 + (fs ^ ((row >> 1) & 3));
            bfh[n] = *(const short8v*)&BsH[cl * 8];
            bfl[n] = *(const short8v*)&BsL[cl * 8];
        }
#pragma unroll
        for (int m = 0; m < 4; ++m)
#pragma unroll
            for (int n = 0; n < 4; ++n) {
                acc[m][n] = __builtin_amdgcn_mfma_f32_16x16x32_bf16(
                    afh[m], bfl[n], acc[m][n], 0, 0, 0);
                acc[m][n] = __builtin_amdgcn_mfma_f32_16x16x32_bf16(
                    afl[m], bfh[n], acc[m][n], 0, 0, 0);
                acc[m][n] = __builtin_amdgcn_mfma_f32_16x16x32_bf16(
                    afh[m], bfh[n], acc[m][n], 0, 0, 0);
            }
    }

    // C/D layout: col = lane&15, row = (lane>>4)*4 + reg   [m89-verified]
#pragma unroll
    for (int m = 0; m < 4; ++m) {
#pragma unroll
        for (int n = 0; n < 4; ++n) {
            int col = bn * 128 + wn * 64 + n * 16 + fr;
#pragma unroll
            for (int r = 0; r < 4; ++r) {
                int rowg = bm * 128 + wm * 64 + m * 16 + fs * 4 + r;
                C_[(size_t)rowg * HDIM + col] = acc[m][n][r];
            }
        }
    }
}

// ---------------- fused aggregate + self + bias + LN + relu (+residual) ----------------
__global__ __launch_bounds__(256) void agg_ln_kernel(
    const float* __restrict__ hi, const float* __restrict__ dis,
    const int* __restrict__ off, const int* __restrict__ csr_src,
    const float* __restrict__ bias, const float* __restrict__ g,
    const float* __restrict__ bln, float* __restrict__ x,
    unsigned short* __restrict__ xh, unsigned short* __restrict__ xl,
    int addResidual)
{
    int gtid = blockIdx.x * blockDim.x + threadIdx.x;
    int n = gtid >> 6;
    int lane = threadIdx.x & 63;
    if (n >= N_NODES) return;
    float dn = dis[n];
    float4 acc = make_float4(0.f, 0.f, 0.f, 0.f);
    int p0 = off[n], p1 = off[n + 1];
    for (int p = p0; p < p1; ++p) {
        int s = csr_src[p];
        float ww = dis[s] * dn;
        float4 v = *(const float4*)(hi + (size_t)s * HDIM + lane * 4);
        acc.x += v.x * ww; acc.y += v.y * ww; acc.z += v.z * ww; acc.w += v.w * ww;
    }
    {
        float ww = dn * dn;
        float4 v = *(const float4*)(hi + (size_t)n * HDIM + lane * 4);
        acc.x += v.x * ww; acc.y += v.y * ww; acc.z += v.z * ww; acc.w += v.w * ww;
    }
    {
        float4 bv = *(const float4*)(bias + lane * 4);
        acc.x += bv.x; acc.y += bv.y; acc.z += bv.z; acc.w += bv.w;
    }
    float s1 = acc.x + acc.y + acc.z + acc.w;
    float s2 = acc.x * acc.x + acc.y * acc.y + acc.z * acc.z + acc.w * acc.w;
#pragma unroll
    for (int m = 1; m < 64; m <<= 1) {
        s1 += __shfl_xor(s1, m);
        s2 += __shfl_xor(s2, m);
    }
    float mu = s1 * (1.0f / 256.0f);
    float var = s2 * (1.0f / 256.0f) - mu * mu;
    float inv = rsqrtf(var + 1e-5f);
    float4 gv = *(const float4*)(g + lane * 4);
    float4 bb = *(const float4*)(bln + lane * 4);
    float4 res;
    res.x = fmaxf((acc.x - mu) * inv * gv.x + bb.x, 0.0f);
    res.y = fmaxf((acc.y - mu) * inv * gv.y + bb.y, 0.0f);
    res.z = fmaxf((acc.z - mu) * inv * gv.z + bb.z, 0.0f);
    res.w = fmaxf((acc.w - mu) * inv * gv.w + bb.w, 0.0f);
    if (addResidual) {
        float4 o = *(const float4*)(x + (size_t)n * HDIM + lane * 4);
        res.x += o.x; res.y += o.y; res.z += o.z; res.w += o.w;
    }
    *(float4*)(x + (size_t)n * HDIM + lane * 4) = res;
    ushort4 h4, l4;
    split_bf(res.x, h4.x, l4.x);
    split_bf(res.y, h4.y, l4.y);
    split_bf(res.z, h4.z, l4.z);
    split_bf(res.w, h4.w, l4.w);
    *(ushort4*)(xh + (size_t)n * HDIM + lane * 4) = h4;
    *(ushort4*)(xl + (size_t)n * HDIM + lane * 4) = l4;
}

// ---------------- cluster-CSR build + atomic-free pooling ----------------
__global__ void ccount_kernel(const int* __restrict__ cluster, int* __restrict__ ccnt) {
    int n = blockIdx.x * blockDim.x + threadIdx.x;
    if (n < N_NODES) atomicAdd(&ccnt[cluster[n]], 1);
}

__global__ __launch_bounds__(1024) void cscan_kernel(const int* __restrict__ ccnt,
                                                     int* __restrict__ coff) {
    __shared__ int part[1024];
    int t = threadIdx.x;
    int s = 0;
    for (int j = 0; j < 4; ++j) s += ccnt[t * 4 + j];
    part[t] = s;
    __syncthreads();
    for (int d = 1; d < 1024; d <<= 1) {
        int v = (t >= d) ? part[t - d] : 0;
        __syncthreads();
        part[t] += v;
        __syncthreads();
    }
    int run = (t == 0) ? 0 : part[t - 1];
    for (int j = 0; j < 4; ++j) {
        coff[t * 4 + j] = run;
        run += ccnt[t * 4 + j];
    }
    if (t == 1023) coff[NCLUST] = run;
}

__global__ void cfill_kernel(const int* __restrict__ cluster, const int* __restrict__ coff,
                             int* __restrict__ ccur, int* __restrict__ cnodes) {
    int n = blockIdx.x * blockDim.x + threadIdx.x;
    if (n >= N_NODES) return;
    int c = cluster[n];
    cnodes[coff[c] + atomicAdd(&ccur[c], 1)] = n;
}

__global__ __launch_bounds__(256) void pool_csr_kernel(const float* __restrict__ x,
                                                       const int* __restrict__ coff,
                                                       const int* __restrict__ cnodes,
                                                       float* __restrict__ pooled) {
    int gtid = blockIdx.x * blockDim.x + threadIdx.x;
    int c = gtid >> 6;
    int lane = threadIdx.x & 63;
    if (c >= NCLUST) return;
    int p0 = coff[c], p1 = coff[c + 1];
    float4 acc = make_float4(0.f, 0.f, 0.f, 0.f);
    for (int p = p0; p < p1; ++p) {
        int n = cnodes[p];
        float4 v = *(const float4*)(x + (size_t)n * HDIM + lane * 4);
        acc.x += v.x; acc.y += v.y; acc.z += v.z; acc.w += v.w;
    }
    float inv = 1.0f / fmaxf((float)(p1 - p0), 1.0f);
    acc.x *= inv; acc.y *= inv; acc.z *= inv; acc.w *= inv;
    *(float4*)(pooled + (size_t)c * HDIM + lane * 4) = acc;
}

__global__ __launch_bounds__(256) void colsq_kernel(const float* __restrict__ pooled,
                                                    float* __restrict__ colsq) {
    int h = threadIdx.x;
    int c0 = blockIdx.x * 16;
    float sq = 0.f;
    for (int cc = 0; cc < 16; ++cc) {
        float v = pooled[(size_t)(c0 + cc) * HDIM + h];
        sq += v * v;
    }
    atomicAdd(&colsq[h], sq);
}

__global__ __launch_bounds__(256) void final_kernel(const float* __restrict__ pooled,
                                                    const float* __restrict__ colsq,
                                                    float* __restrict__ out) {
    int i = blockIdx.x * blockDim.x + threadIdx.x;
    if (i >= NCLUST * HDIM) return;
    int h = i & (HDIM - 1);
    float nrm = fmaxf(sqrtf(colsq[h]), 1e-6f);
    out[i] = pooled[i] / nrm;
}

extern "C" void kernel_launch(void* const* d_in, const int* in_sizes, int n_in,
                              void* d_out, int out_size, void* d_ws, size_t ws_size,
                              hipStream_t stream) {
    const float* x_geo   = (const float*)d_in[0];
    const int*   id_index = (const int*)d_in[1];
    const int*   edge_index = (const int*)d_in[2];
    const int*   cluster = (const int*)d_in[3];
    const float* id_emb  = (const float*)d_in[4];
    const float* enc_w1  = (const float*)d_in[5];
    const float* enc_b1  = (const float*)d_in[6];
    const float* enc_w2  = (const float*)d_in[7];
    const float* enc_b2  = (const float*)d_in[8];
    const float* enc_w3  = (const float*)d_in[9];
    const float* enc_b3  = (const float*)d_in[10];
    const float* skip_w  = (const float*)d_in[11];
    const float* skip_b  = (const float*)d_in[12];
    const float* gcn_w   = (const float*)d_in[13];
    const float* gcn_b   = (const float*)d_in[14];
    const float* ln_g    = (const float*)d_in[15];
    const float* ln_b    = (const float*)d_in[16];
    float* out = (float*)d_out;

    char* ws = (char*)d_ws;
    size_t o = 0;
    auto alloc = [&](size_t bytes) {
        char* p = ws + o;
        o += (bytes + 255) & ~(size_t)255;
        return p;
    };
    float*          x      = (float*)alloc((size_t)N_NODES * HDIM * 4);
    float*          hi     = (float*)alloc((size_t)N_NODES * HDIM * 4);
    unsigned short* xh     = (unsigned short*)alloc((size_t)N_NODES * HDIM * 2);
    unsigned short* xl     = (unsigned short*)alloc((size_t)N_NODES * HDIM * 2);
    unsigned short* wth    = (unsigned short*)alloc((size_t)NLAYERS * HDIM * HDIM * 2);
    unsigned short* wtl    = (unsigned short*)alloc((size_t)NLAYERS * HDIM * HDIM * 2);
    int*   degi    = (int*)alloc((size_t)N_NODES * 4);
    float* dis     = (float*)alloc((size_t)N_NODES * 4);
    int*   off     = (int*)alloc((size_t)(N_NODES + 1) * 4);
    int*   cursor  = (int*)alloc((size_t)N_NODES * 4);
    int*   csr_src = (int*)alloc((size_t)N_EDGES * 4);
    int*   ccnt    = (int*)alloc((size_t)NCLUST * 4);
    int*   coff    = (int*)alloc((size_t)(NCLUST + 1) * 4);
    int*   ccur    = (int*)alloc((size_t)NCLUST * 4);
    int*   cnodes  = (int*)alloc((size_t)N_NODES * 4);
    float* pooled  = (float*)alloc((size_t)NCLUST * HDIM * 4);
    float* colsq   = (float*)alloc((size_t)256 * 4);

    const int* esrc = edge_index;
    const int* edst = edge_index + N_EDGES;

    hipMemsetAsync(degi, 0, (size_t)N_NODES * 4, stream);
    hipMemsetAsync(cursor, 0, (size_t)N_NODES * 4, stream);
    hipMemsetAsync(ccnt, 0, (size_t)NCLUST * 4, stream);
    hipMemsetAsync(ccur, 0, (size_t)NCLUST * 4, stream);
    hipMemsetAsync(colsq, 0, (size_t)256 * 4, stream);

    encoder_kernel<<<N_NODES / 4, 256, 0, stream>>>(
        x_geo, id_index, id_emb, enc_w1, enc_b1, enc_w2, enc_b2, enc_w3, enc_b3,
        skip_w, skip_b, x, xh, xl);

    wtrans_kernel<<<dim3(8, NLAYERS), 256, 0, stream>>>(gcn_w, wth, wtl);

    count_kernel<<<N_EDGES / 256, 256, 0, stream>>>(edst, degi);
    dis_kernel<<<N_NODES / 256, 256, 0, stream>>>(degi, dis);
    scan_kernel<<<1, 1024, 0, stream>>>(degi, off);
    fill_kernel<<<N_EDGES / 256, 256, 0, stream>>>(esrc, edst, off, cursor, csr_src);

    ccount_kernel<<<N_NODES / 256, 256, 0, stream>>>(cluster, ccnt);
    cscan_kernel<<<1, 1024, 0, stream>>>(ccnt, coff);
    cfill_kernel<<<N_NODES / 256, 256, 0, stream>>>(cluster, coff, ccur, cnodes);

    for (int i = 0; i < NLAYERS; ++i) {
        mfma_gemm_kernel<<<dim3(HDIM / 128, N_NODES / 128), 256, 0, stream>>>(
            xh, xl, wth + (size_t)i * HDIM * HDIM, wtl + (size_t)i * HDIM * HDIM, hi);
        agg_ln_kernel<<<N_NODES / 4, 256, 0, stream>>>(
            hi, dis, off, csr_src, gcn_b + (size_t)i * HDIM,
            ln_g + (size_t)i * HDIM, ln_b + (size_t)i * HDIM, x, xh, xl, (i == 0) ? 1 : 0);
    }

    pool_csr_kernel<<<NCLUST / 4, 256, 0, stream>>>(x, coff, cnodes, pooled);
    colsq_kernel<<<NCLUST / 16, 256, 0, stream>>>(pooled, colsq);
    final_kernel<<<NCLUST * HDIM / 256, 256, 0, stream>>>(pooled, colsq, out);
}

// Round 6
// 2012.538 us; speedup vs baseline: 1.2762x; 1.0976x over previous
//
#include <hip/hip_runtime.h>
#include <math.h>

#define N_NODES 65536
#define N_EDGES 524288
#define HDIM 256
#define NLAYERS 9
#define NCLUST 4096
#define HQ 64
#define INCF 11

typedef __attribute__((ext_vector_type(8))) short short8v;
typedef __attribute__((ext_vector_type(4))) float f32x4;

__device__ __forceinline__ float gelu_exact(float v) {
    return 0.5f * v * (1.0f + erff(v * 0.70710678118654752440f));
}

__device__ __forceinline__ unsigned short f2bf(float f) {
    union { float f; unsigned u; } a; a.f = f;
    unsigned r = a.u + 0x7FFFu + ((a.u >> 16) & 1u);  // round-nearest-even
    return (unsigned short)(r >> 16);
}

__device__ __forceinline__ float bf2f(unsigned short h) {
    union { unsigned u; float f; } a; a.u = ((unsigned)h) << 16;
    return a.f;
}

__device__ __forceinline__ void split_bf(float v, unsigned short& h, unsigned short& l) {
    h = f2bf(v);
    l = f2bf(v - bf2f(h));
}

// ---------------- encoder v2: wave per 4 nodes (amortize weight L2 traffic 4x) ----------------
__global__ __launch_bounds__(256) void encoder_kernel(
    const float* __restrict__ x_geo, const int* __restrict__ id_index,
    const float* __restrict__ id_emb,
    const float* __restrict__ w1, const float* __restrict__ b1,
    const float* __restrict__ w2, const float* __restrict__ b2,
    const float* __restrict__ w3, const float* __restrict__ b3,
    const float* __restrict__ sw, const float* __restrict__ sb,
    unsigned short* __restrict__ xh, unsigned short* __restrict__ xl)
{
    int wid = blockIdx.x * 4 + (threadIdx.x >> 6);
    int lane = threadIdx.x & 63;
    int nbase = wid * 4;
    if (nbase >= N_NODES) return;

    float nf[4][INCF];
#pragma unroll
    for (int j = 0; j < 4; ++j) {
        int node = nbase + j;
        nf[j][0] = x_geo[node * 3 + 0];
        nf[j][1] = x_geo[node * 3 + 1];
        nf[j][2] = x_geo[node * 3 + 2];
        int idv = id_index[node];
#pragma unroll
        for (int k = 0; k < 8; ++k) nf[j][3 + k] = id_emb[idv * 8 + k];
    }

    // h1 = gelu(node @ w1 + b1), lane owns h1[t] for each of 4 nodes
    float h1[4];
    {
        float b = b1[lane];
        float a0 = b, a1 = b, a2 = b, a3 = b;
#pragma unroll
        for (int k = 0; k < INCF; ++k) {
            float wv = w1[k * HQ + lane];
            a0 += nf[0][k] * wv; a1 += nf[1][k] * wv;
            a2 += nf[2][k] * wv; a3 += nf[3][k] * wv;
        }
        h1[0] = gelu_exact(a0); h1[1] = gelu_exact(a1);
        h1[2] = gelu_exact(a2); h1[3] = gelu_exact(a3);
    }

    float h2[4];
    {
        float b = b2[lane];
        float a0 = b, a1 = b, a2 = b, a3 = b;
        for (int k = 0; k < HQ; ++k) {
            float wv = w2[k * HQ + lane];
            a0 += __shfl(h1[0], k) * wv; a1 += __shfl(h1[1], k) * wv;
            a2 += __shfl(h1[2], k) * wv; a3 += __shfl(h1[3], k) * wv;
        }
        h2[0] = gelu_exact(a0); h2[1] = gelu_exact(a1);
        h2[2] = gelu_exact(a2); h2[3] = gelu_exact(a3);
    }

    // a4[j][j0]: out = gelu(node@sw + sb + h2@w3 + b3)
    float a4[4][4];
#pragma unroll
    for (int j0 = 0; j0 < 4; ++j0) {
        float b = b3[j0 * 64 + lane] + sb[j0 * 64 + lane];
#pragma unroll
        for (int j = 0; j < 4; ++j) a4[j][j0] = b;
    }
    for (int k = 0; k < HQ; ++k) {
        float wv0 = w3[k * HDIM + 0 * 64 + lane];
        float wv1 = w3[k * HDIM + 1 * 64 + lane];
        float wv2 = w3[k * HDIM + 2 * 64 + lane];
        float wv3 = w3[k * HDIM + 3 * 64 + lane];
#pragma unroll
        for (int j = 0; j < 4; ++j) {
            float hk = __shfl(h2[j], k);
            a4[j][0] += hk * wv0; a4[j][1] += hk * wv1;
            a4[j][2] += hk * wv2; a4[j][3] += hk * wv3;
        }
    }
#pragma unroll
    for (int k = 0; k < INCF; ++k) {
        float wv0 = sw[k * HDIM + 0 * 64 + lane];
        float wv1 = sw[k * HDIM + 1 * 64 + lane];
        float wv2 = sw[k * HDIM + 2 * 64 + lane];
        float wv3 = sw[k * HDIM + 3 * 64 + lane];
#pragma unroll
        for (int j = 0; j < 4; ++j) {
            float nk = nf[j][k];
            a4[j][0] += nk * wv0; a4[j][1] += nk * wv1;
            a4[j][2] += nk * wv2; a4[j][3] += nk * wv3;
        }
    }
#pragma unroll
    for (int j = 0; j < 4; ++j) {
        int node = nbase + j;
#pragma unroll
        for (int j0 = 0; j0 < 4; ++j0) {
            float v = gelu_exact(a4[j][j0]);
            unsigned short h, l;
            split_bf(v, h, l);
            xh[(size_t)node * HDIM + j0 * 64 + lane] = h;
            xl[(size_t)node * HDIM + j0 * 64 + lane] = l;
        }
    }
}

// ---------------- degree / edge-CSR build ----------------
__global__ void count_kernel(const int* __restrict__ dst, int* __restrict__ degi) {
    int e = blockIdx.x * blockDim.x + threadIdx.x;
    if (e < N_EDGES) atomicAdd(&degi[dst[e]], 1);
}

__global__ void dis_kernel(const int* __restrict__ degi, float* __restrict__ dis) {
    int n = blockIdx.x * blockDim.x + threadIdx.x;
    if (n < N_NODES) dis[n] = rsqrtf((float)degi[n] + 1.0f);
}

__global__ __launch_bounds__(1024) void scan_kernel(const int* __restrict__ degi,
                                                    int* __restrict__ off) {
    __shared__ int part[1024];
    int t = threadIdx.x;
    int base = t * 64;
    int s = 0;
    for (int j = 0; j < 64; ++j) s += degi[base + j];
    part[t] = s;
    __syncthreads();
    for (int d = 1; d < 1024; d <<= 1) {
        int v = (t >= d) ? part[t - d] : 0;
        __syncthreads();
        part[t] += v;
        __syncthreads();
    }
    int run = (t == 0) ? 0 : part[t - 1];
    for (int j = 0; j < 64; ++j) {
        off[base + j] = run;
        run += degi[base + j];
    }
    if (t == 1023) off[N_NODES] = run;
}

__global__ void fill_kernel(const int* __restrict__ src, const int* __restrict__ dst,
                            const int* __restrict__ off, int* __restrict__ cursor,
                            int* __restrict__ csr_src) {
    int e = blockIdx.x * blockDim.x + threadIdx.x;
    if (e >= N_EDGES) return;
    int d = dst[e];
    int pos = off[d] + atomicAdd(&cursor[d], 1);
    csr_src[pos] = src[e];
}

// ---------------- weight transpose + bf16 hi/lo: wt[l][n][k] = w[l][k][n] ----------------
__global__ __launch_bounds__(256) void wtrans_kernel(const float* __restrict__ w,
                                                     unsigned short* __restrict__ wth,
                                                     unsigned short* __restrict__ wtl_) {
    __shared__ float t[32][257];
    int l = blockIdx.y, kb = blockIdx.x;
    const float* wl = w + (size_t)l * HDIM * HDIM + (size_t)kb * 32 * HDIM;
#pragma unroll
    for (int it = 0; it < 32; ++it) {
        int idx = it * 256 + threadIdx.x;
        t[idx >> 8][idx & 255] = wl[idx];
    }
    __syncthreads();
    unsigned short* wh = wth + (size_t)l * HDIM * HDIM + kb * 32;
    unsigned short* wl2 = wtl_ + (size_t)l * HDIM * HDIM + kb * 32;
    int k = threadIdx.x & 31, n0 = threadIdx.x >> 5;
#pragma unroll
    for (int it = 0; it < 32; ++it) {
        int n = it * 8 + n0;
        unsigned short h, lo;
        split_bf(t[k][n], h, lo);
        wh[(size_t)n * HDIM + k] = h;
        wl2[(size_t)n * HDIM + k] = lo;
    }
}

// ---------------- bf16x3 MFMA GEMM: hi = x @ W with hi/lo error compensation ----------------
__global__ __launch_bounds__(256) void mfma_gemm_kernel(
    const unsigned short* __restrict__ Ah, const unsigned short* __restrict__ Al,
    const unsigned short* __restrict__ Bh, const unsigned short* __restrict__ Bl,
    float* __restrict__ C_)
{
    __shared__ unsigned short AsH[128 * 32];
    __shared__ unsigned short AsL[128 * 32];
    __shared__ unsigned short BsH[128 * 32];
    __shared__ unsigned short BsL[128 * 32];
    int tid = threadIdx.x;
    int w = tid >> 6, l = tid & 63;
    int bn = blockIdx.x, bm = blockIdx.y;
    int wm = w >> 1, wn = w & 1;
    int fr = l & 15, fs = l >> 4;

    f32x4 acc[4][4];
#pragma unroll
    for (int m = 0; m < 4; ++m)
#pragma unroll
        for (int n = 0; n < 4; ++n) acc[m][n] = (f32x4){0.f, 0.f, 0.f, 0.f};

    const size_t aoff = (size_t)(bm * 128) * HDIM;
    const size_t boff = (size_t)(bn * 128) * HDIM;

#pragma unroll
    for (int k0 = 0; k0 < HDIM; k0 += 32) {
        uint4 vah[2], val[2], vbh[2], vbl[2];
#pragma unroll
        for (int j = 0; j < 2; ++j) {
            int s = j * 256 + tid;
            int row = s >> 2, sub = s & 3;
            size_t g = (size_t)row * HDIM + k0 + sub * 8;
            vah[j] = *(const uint4*)(Ah + aoff + g);
            val[j] = *(const uint4*)(Al + aoff + g);
            vbh[j] = *(const uint4*)(Bh + boff + g);
            vbl[j] = *(const uint4*)(Bl + boff + g);
        }
        __syncthreads();
#pragma unroll
        for (int j = 0; j < 2; ++j) {
            int s = j * 256 + tid;
            int row = s >> 2, sub = s & 3;
            int cl = row * 4 + (sub ^ ((row >> 1) & 3));
            *(uint4*)&AsH[cl * 8] = vah[j];
            *(uint4*)&AsL[cl * 8] = val[j];
            *(uint4*)&BsH[cl * 8] = vbh[j];
            *(uint4*)&BsL[cl * 8] = vbl[j];
        }
        __syncthreads();

        short8v afh[4], afl[4], bfh[4], bfl[4];
#pragma unroll
        for (int m = 0; m < 4; ++m) {
            int row = wm * 64 + m * 16 + fr;
            int cl = row * 4 + (fs ^ ((row >> 1) & 3));
            afh[m] = *(const short8v*)&AsH[cl * 8];
            afl[m] = *(const short8v*)&AsL[cl * 8];
        }
#pragma unroll
        for (int n = 0; n < 4; ++n) {
            int row = wn * 64 + n * 16 + fr;
            int cl = row * 4 + (fs ^ ((row >> 1) & 3));
            bfh[n] = *(const short8v*)&BsH[cl * 8];
            bfl[n] = *(const short8v*)&BsL[cl * 8];
        }
#pragma unroll
        for (int m = 0; m < 4; ++m)
#pragma unroll
            for (int n = 0; n < 4; ++n) {
                acc[m][n] = __builtin_amdgcn_mfma_f32_16x16x32_bf16(
                    afh[m], bfl[n], acc[m][n], 0, 0, 0);
                acc[m][n] = __builtin_amdgcn_mfma_f32_16x16x32_bf16(
                    afl[m], bfh[n], acc[m][n], 0, 0, 0);
                acc[m][n] = __builtin_amdgcn_mfma_f32_16x16x32_bf16(
                    afh[m], bfh[n], acc[m][n], 0, 0, 0);
            }
    }

#pragma unroll
    for (int m = 0; m < 4; ++m) {
#pragma unroll
        for (int n = 0; n < 4; ++n) {
            int col = bn * 128 + wn * 64 + n * 16 + fr;
#pragma unroll
            for (int r = 0; r < 4; ++r) {
                int rowg = bm * 128 + wm * 64 + m * 16 + fs * 4 + r;
                C_[(size_t)rowg * HDIM + col] = acc[m][n][r];
            }
        }
    }
}

// ---------------- fused aggregate + LN + relu (+residual), 4-deep pipelined gather ----------------
__global__ __launch_bounds__(256) void agg_ln_kernel(
    const float* __restrict__ hi, const float* __restrict__ dis,
    const int* __restrict__ off, const int* __restrict__ csr_src,
    const float* __restrict__ bias, const float* __restrict__ g,
    const float* __restrict__ bln,
    unsigned short* __restrict__ xh, unsigned short* __restrict__ xl,
    int addResidual)
{
    int gtid = blockIdx.x * blockDim.x + threadIdx.x;
    int n = gtid >> 6;
    int lane = threadIdx.x & 63;
    if (n >= N_NODES) return;
    float dn = dis[n];
    int p0 = off[n], p1 = off[n + 1];
    int deg = p1 - p0;
    // issue independent loads early
    float4 vself = *(const float4*)(hi + (size_t)n * HDIM + lane * 4);
    float4 bv = *(const float4*)(bias + lane * 4);
    float4 gv = *(const float4*)(g + lane * 4);
    float4 bb = *(const float4*)(bln + lane * 4);

    float4 acc = make_float4(0.f, 0.f, 0.f, 0.f);
    // 4-deep pipelined gather (named slots; no runtime-indexed arrays)
    float4 v0, v1, v2, v3;
    float wt0 = 0.f, wt1 = 0.f, wt2 = 0.f, wt3 = 0.f;
    if (deg > 0) { int s = csr_src[p0 + 0]; wt0 = dis[s]; v0 = *(const float4*)(hi + (size_t)s * HDIM + lane * 4); }
    if (deg > 1) { int s = csr_src[p0 + 1]; wt1 = dis[s]; v1 = *(const float4*)(hi + (size_t)s * HDIM + lane * 4); }
    if (deg > 2) { int s = csr_src[p0 + 2]; wt2 = dis[s]; v2 = *(const float4*)(hi + (size_t)s * HDIM + lane * 4); }
    if (deg > 3) { int s = csr_src[p0 + 3]; wt3 = dis[s]; v3 = *(const float4*)(hi + (size_t)s * HDIM + lane * 4); }
    int pp = 0;
    for (; pp + 4 <= deg; pp += 4) {
        float4 v = v0; float wv = wt0 * dn;
        if (pp + 4 < deg) { int s = csr_src[p0 + pp + 4]; wt0 = dis[s]; v0 = *(const float4*)(hi + (size_t)s * HDIM + lane * 4); }
        acc.x += v.x * wv; acc.y += v.y * wv; acc.z += v.z * wv; acc.w += v.w * wv;
        v = v1; wv = wt1 * dn;
        if (pp + 5 < deg) { int s = csr_src[p0 + pp + 5]; wt1 = dis[s]; v1 = *(const float4*)(hi + (size_t)s * HDIM + lane * 4); }
        acc.x += v.x * wv; acc.y += v.y * wv; acc.z += v.z * wv; acc.w += v.w * wv;
        v = v2; wv = wt2 * dn;
        if (pp + 6 < deg) { int s = csr_src[p0 + pp + 6]; wt2 = dis[s]; v2 = *(const float4*)(hi + (size_t)s * HDIM + lane * 4); }
        acc.x += v.x * wv; acc.y += v.y * wv; acc.z += v.z * wv; acc.w += v.w * wv;
        v = v3; wv = wt3 * dn;
        if (pp + 7 < deg) { int s = csr_src[p0 + pp + 7]; wt3 = dis[s]; v3 = *(const float4*)(hi + (size_t)s * HDIM + lane * 4); }
        acc.x += v.x * wv; acc.y += v.y * wv; acc.z += v.z * wv; acc.w += v.w * wv;
    }
    int r = deg - pp;
    if (r > 0) { float wv = wt0 * dn; acc.x += v0.x * wv; acc.y += v0.y * wv; acc.z += v0.z * wv; acc.w += v0.w * wv; }
    if (r > 1) { float wv = wt1 * dn; acc.x += v1.x * wv; acc.y += v1.y * wv; acc.z += v1.z * wv; acc.w += v1.w * wv; }
    if (r > 2) { float wv = wt2 * dn; acc.x += v2.x * wv; acc.y += v2.y * wv; acc.z += v2.z * wv; acc.w += v2.w * wv; }

    {
        float wv = dn * dn;
        acc.x += vself.x * wv + bv.x;
        acc.y += vself.y * wv + bv.y;
        acc.z += vself.z * wv + bv.z;
        acc.w += vself.w * wv + bv.w;
    }
    float s1 = acc.x + acc.y + acc.z + acc.w;
    float s2 = acc.x * acc.x + acc.y * acc.y + acc.z * acc.z + acc.w * acc.w;
#pragma unroll
    for (int m = 1; m < 64; m <<= 1) {
        s1 += __shfl_xor(s1, m);
        s2 += __shfl_xor(s2, m);
    }
    float mu = s1 * (1.0f / 256.0f);
    float var = s2 * (1.0f / 256.0f) - mu * mu;
    float inv = rsqrtf(var + 1e-5f);
    float4 res;
    res.x = fmaxf((acc.x - mu) * inv * gv.x + bb.x, 0.0f);
    res.y = fmaxf((acc.y - mu) * inv * gv.y + bb.y, 0.0f);
    res.z = fmaxf((acc.z - mu) * inv * gv.z + bb.z, 0.0f);
    res.w = fmaxf((acc.w - mu) * inv * gv.w + bb.w, 0.0f);
    if (addResidual) {
        ushort4 oh = *(const ushort4*)(xh + (size_t)n * HDIM + lane * 4);
        ushort4 ol = *(const ushort4*)(xl + (size_t)n * HDIM + lane * 4);
        res.x += bf2f(oh.x) + bf2f(ol.x);
        res.y += bf2f(oh.y) + bf2f(ol.y);
        res.z += bf2f(oh.z) + bf2f(ol.z);
        res.w += bf2f(oh.w) + bf2f(ol.w);
    }
    ushort4 h4, l4;
    split_bf(res.x, h4.x, l4.x);
    split_bf(res.y, h4.y, l4.y);
    split_bf(res.z, h4.z, l4.z);
    split_bf(res.w, h4.w, l4.w);
    *(ushort4*)(xh + (size_t)n * HDIM + lane * 4) = h4;
    *(ushort4*)(xl + (size_t)n * HDIM + lane * 4) = l4;
}

// ---------------- cluster-CSR build + atomic-free pooling ----------------
__global__ void ccount_kernel(const int* __restrict__ cluster, int* __restrict__ ccnt) {
    int n = blockIdx.x * blockDim.x + threadIdx.x;
    if (n < N_NODES) atomicAdd(&ccnt[cluster[n]], 1);
}

__global__ __launch_bounds__(1024) void cscan_kernel(const int* __restrict__ ccnt,
                                                     int* __restrict__ coff) {
    __shared__ int part[1024];
    int t = threadIdx.x;
    int s = 0;
    for (int j = 0; j < 4; ++j) s += ccnt[t * 4 + j];
    part[t] = s;
    __syncthreads();
    for (int d = 1; d < 1024; d <<= 1) {
        int v = (t >= d) ? part[t - d] : 0;
        __syncthreads();
        part[t] += v;
        __syncthreads();
    }
    int run = (t == 0) ? 0 : part[t - 1];
    for (int j = 0; j < 4; ++j) {
        coff[t * 4 + j] = run;
        run += ccnt[t * 4 + j];
    }
    if (t == 1023) coff[NCLUST] = run;
}

__global__ void cfill_kernel(const int* __restrict__ cluster, const int* __restrict__ coff,
                             int* __restrict__ ccur, int* __restrict__ cnodes) {
    int n = blockIdx.x * blockDim.x + threadIdx.x;
    if (n >= N_NODES) return;
    int c = cluster[n];
    cnodes[coff[c] + atomicAdd(&ccur[c], 1)] = n;
}

__global__ __launch_bounds__(256) void pool_csr_kernel(const unsigned short* __restrict__ xh,
                                                       const unsigned short* __restrict__ xl,
                                                       const int* __restrict__ coff,
                                                       const int* __restrict__ cnodes,
                                                       float* __restrict__ pooled) {
    int gtid = blockIdx.x * blockDim.x + threadIdx.x;
    int c = gtid >> 6;
    int lane = threadIdx.x & 63;
    if (c >= NCLUST) return;
    int p0 = coff[c], p1 = coff[c + 1];
    float4 acc = make_float4(0.f, 0.f, 0.f, 0.f);
    for (int p = p0; p < p1; ++p) {
        int n = cnodes[p];
        ushort4 h4 = *(const ushort4*)(xh + (size_t)n * HDIM + lane * 4);
        ushort4 l4 = *(const ushort4*)(xl + (size_t)n * HDIM + lane * 4);
        acc.x += bf2f(h4.x) + bf2f(l4.x);
        acc.y += bf2f(h4.y) + bf2f(l4.y);
        acc.z += bf2f(h4.z) + bf2f(l4.z);
        acc.w += bf2f(h4.w) + bf2f(l4.w);
    }
    float inv = 1.0f / fmaxf((float)(p1 - p0), 1.0f);
    acc.x *= inv; acc.y *= inv; acc.z *= inv; acc.w *= inv;
    *(float4*)(pooled + (size_t)c * HDIM + lane * 4) = acc;
}

__global__ __launch_bounds__(256) void colsq_kernel(const float* __restrict__ pooled,
                                                    float* __restrict__ colsq) {
    int h = threadIdx.x;
    int c0 = blockIdx.x * 16;
    float sq = 0.f;
    for (int cc = 0; cc < 16; ++cc) {
        float v = pooled[(size_t)(c0 + cc) * HDIM + h];
        sq += v * v;
    }
    atomicAdd(&colsq[h], sq);
}

__global__ __launch_bounds__(256) void final_kernel(const float* __restrict__ pooled,
                                                    const float* __restrict__ colsq,
                                                    float* __restrict__ out) {
    int i = blockIdx.x * blockDim.x + threadIdx.x;
    if (i >= NCLUST * HDIM) return;
    int h = i & (HDIM - 1);
    float nrm = fmaxf(sqrtf(colsq[h]), 1e-6f);
    out[i] = pooled[i] / nrm;
}

extern "C" void kernel_launch(void* const* d_in, const int* in_sizes, int n_in,
                              void* d_out, int out_size, void* d_ws, size_t ws_size,
                              hipStream_t stream) {
    const float* x_geo   = (const float*)d_in[0];
    const int*   id_index = (const int*)d_in[1];
    const int*   edge_index = (const int*)d_in[2];
    const int*   cluster = (const int*)d_in[3];
    const float* id_emb  = (const float*)d_in[4];
    const float* enc_w1  = (const float*)d_in[5];
    const float* enc_b1  = (const float*)d_in[6];
    const float* enc_w2  = (const float*)d_in[7];
    const float* enc_b2  = (const float*)d_in[8];
    const float* enc_w3  = (const float*)d_in[9];
    const float* enc_b3  = (const float*)d_in[10];
    const float* skip_w  = (const float*)d_in[11];
    const float* skip_b  = (const float*)d_in[12];
    const float* gcn_w   = (const float*)d_in[13];
    const float* gcn_b   = (const float*)d_in[14];
    const float* ln_g    = (const float*)d_in[15];
    const float* ln_b    = (const float*)d_in[16];
    float* out = (float*)d_out;

    char* ws = (char*)d_ws;
    size_t o = 0;
    auto alloc = [&](size_t bytes) {
        char* p = ws + o;
        o += (bytes + 255) & ~(size_t)255;
        return p;
    };
    float*          hi     = (float*)alloc((size_t)N_NODES * HDIM * 4);
    unsigned short* xh     = (unsigned short*)alloc((size_t)N_NODES * HDIM * 2);
    unsigned short* xl     = (unsigned short*)alloc((size_t)N_NODES * HDIM * 2);
    unsigned short* wth    = (unsigned short*)alloc((size_t)NLAYERS * HDIM * HDIM * 2);
    unsigned short* wtl    = (unsigned short*)alloc((size_t)NLAYERS * HDIM * HDIM * 2);
    int*   degi    = (int*)alloc((size_t)N_NODES * 4);
    float* dis     = (float*)alloc((size_t)N_NODES * 4);
    int*   off     = (int*)alloc((size_t)(N_NODES + 1) * 4);
    int*   cursor  = (int*)alloc((size_t)N_NODES * 4);
    int*   csr_src = (int*)alloc((size_t)N_EDGES * 4);
    int*   ccnt    = (int*)alloc((size_t)NCLUST * 4);
    int*   coff    = (int*)alloc((size_t)(NCLUST + 1) * 4);
    int*   ccur    = (int*)alloc((size_t)NCLUST * 4);
    int*   cnodes  = (int*)alloc((size_t)N_NODES * 4);
    float* pooled  = (float*)alloc((size_t)NCLUST * HDIM * 4);
    float* colsq   = (float*)alloc((size_t)256 * 4);

    const int* esrc = edge_index;
    const int* edst = edge_index + N_EDGES;

    hipMemsetAsync(degi, 0, (size_t)N_NODES * 4, stream);
    hipMemsetAsync(cursor, 0, (size_t)N_NODES * 4, stream);
    hipMemsetAsync(ccnt, 0, (size_t)NCLUST * 4, stream);
    hipMemsetAsync(ccur, 0, (size_t)NCLUST * 4, stream);
    hipMemsetAsync(colsq, 0, (size_t)256 * 4, stream);

    encoder_kernel<<<N_NODES / 16, 256, 0, stream>>>(
        x_geo, id_index, id_emb, enc_w1, enc_b1, enc_w2, enc_b2, enc_w3, enc_b3,
        skip_w, skip_b, xh, xl);

    wtrans_kernel<<<dim3(8, NLAYERS), 256, 0, stream>>>(gcn_w, wth, wtl);

    count_kernel<<<N_EDGES / 256, 256, 0, stream>>>(edst, degi);
    dis_kernel<<<N_NODES / 256, 256, 0, stream>>>(degi, dis);
    scan_kernel<<<1, 1024, 0, stream>>>(degi, off);
    fill_kernel<<<N_EDGES / 256, 256, 0, stream>>>(esrc, edst, off, cursor, csr_src);

    ccount_kernel<<<N_NODES / 256, 256, 0, stream>>>(cluster, ccnt);
    cscan_kernel<<<1, 1024, 0, stream>>>(ccnt, coff);
    cfill_kernel<<<N_NODES / 256, 256, 0, stream>>>(cluster, coff, ccur, cnodes);

    for (int i = 0; i < NLAYERS; ++i) {
        mfma_gemm_kernel<<<dim3(HDIM / 128, N_NODES / 128), 256, 0, stream>>>(
            xh, xl, wth + (size_t)i * HDIM * HDIM, wtl + (size_t)i * HDIM * HDIM, hi);
        agg_ln_kernel<<<N_NODES / 4, 256, 0, stream>>>(
            hi, dis, off, csr_src, gcn_b + (size_t)i * HDIM,
            ln_g + (size_t)i * HDIM, ln_b + (size_t)i * HDIM, xh, xl, (i == 0) ? 1 : 0);
    }

    pool_csr_kernel<<<NCLUST / 4, 256, 0, stream>>>(xh, xl, coff, cnodes, pooled);
    colsq_kernel<<<NCLUST / 16, 256, 0, stream>>>(pooled, colsq);
    final_kernel<<<NCLUST * HDIM / 256, 256, 0, stream>>>(pooled, colsq, out);
}

// Round 10
// 1706.517 us; speedup vs baseline: 1.5051x; 1.1793x over previous
//
#include <hip/hip_runtime.h>
#include <math.h>

#define N_NODES 65536
#define N_EDGES 524288
#define HDIM 256
#define NLAYERS 9
#define NCLUST 4096
#define HQ 64
#define INCF 11

typedef __attribute__((ext_vector_type(8))) short short8v;
typedef __attribute__((ext_vector_type(4))) float f32x4;

__device__ __forceinline__ float gelu_exact(float v) {
    return 0.5f * v * (1.0f + erff(v * 0.70710678118654752440f));
}

__device__ __forceinline__ unsigned short f2bf(float f) {
    union { float f; unsigned u; } a; a.f = f;
    unsigned r = a.u + 0x7FFFu + ((a.u >> 16) & 1u);  // round-nearest-even
    return (unsigned short)(r >> 16);
}

__device__ __forceinline__ float bf2f(unsigned short h) {
    union { unsigned u; float f; } a; a.u = ((unsigned)h) << 16;
    return a.f;
}

__device__ __forceinline__ void split_bf(float v, unsigned short& h, unsigned short& l) {
    h = f2bf(v);
    l = f2bf(v - bf2f(h));
}

// ---------------- encoder v2: wave per 4 nodes ----------------
__global__ __launch_bounds__(256) void encoder_kernel(
    const float* __restrict__ x_geo, const int* __restrict__ id_index,
    const float* __restrict__ id_emb,
    const float* __restrict__ w1, const float* __restrict__ b1,
    const float* __restrict__ w2, const float* __restrict__ b2,
    const float* __restrict__ w3, const float* __restrict__ b3,
    const float* __restrict__ sw, const float* __restrict__ sb,
    unsigned short* __restrict__ xh, unsigned short* __restrict__ xl)
{
    int wid = blockIdx.x * 4 + (threadIdx.x >> 6);
    int lane = threadIdx.x & 63;
    int nbase = wid * 4;
    if (nbase >= N_NODES) return;

    float nf[4][INCF];
#pragma unroll
    for (int j = 0; j < 4; ++j) {
        int node = nbase + j;
        nf[j][0] = x_geo[node * 3 + 0];
        nf[j][1] = x_geo[node * 3 + 1];
        nf[j][2] = x_geo[node * 3 + 2];
        int idv = id_index[node];
#pragma unroll
        for (int k = 0; k < 8; ++k) nf[j][3 + k] = id_emb[idv * 8 + k];
    }

    float h1[4];
    {
        float b = b1[lane];
        float a0 = b, a1 = b, a2 = b, a3 = b;
#pragma unroll
        for (int k = 0; k < INCF; ++k) {
            float wv = w1[k * HQ + lane];
            a0 += nf[0][k] * wv; a1 += nf[1][k] * wv;
            a2 += nf[2][k] * wv; a3 += nf[3][k] * wv;
        }
        h1[0] = gelu_exact(a0); h1[1] = gelu_exact(a1);
        h1[2] = gelu_exact(a2); h1[3] = gelu_exact(a3);
    }

    float h2[4];
    {
        float b = b2[lane];
        float a0 = b, a1 = b, a2 = b, a3 = b;
        for (int k = 0; k < HQ; ++k) {
            float wv = w2[k * HQ + lane];
            a0 += __shfl(h1[0], k) * wv; a1 += __shfl(h1[1], k) * wv;
            a2 += __shfl(h1[2], k) * wv; a3 += __shfl(h1[3], k) * wv;
        }
        h2[0] = gelu_exact(a0); h2[1] = gelu_exact(a1);
        h2[2] = gelu_exact(a2); h2[3] = gelu_exact(a3);
    }

    float a4[4][4];
#pragma unroll
    for (int j0 = 0; j0 < 4; ++j0) {
        float b = b3[j0 * 64 + lane] + sb[j0 * 64 + lane];
#pragma unroll
        for (int j = 0; j < 4; ++j) a4[j][j0] = b;
    }
    for (int k = 0; k < HQ; ++k) {
        float wv0 = w3[k * HDIM + 0 * 64 + lane];
        float wv1 = w3[k * HDIM + 1 * 64 + lane];
        float wv2 = w3[k * HDIM + 2 * 64 + lane];
        float wv3 = w3[k * HDIM + 3 * 64 + lane];
#pragma unroll
        for (int j = 0; j < 4; ++j) {
            float hk = __shfl(h2[j], k);
            a4[j][0] += hk * wv0; a4[j][1] += hk * wv1;
            a4[j][2] += hk * wv2; a4[j][3] += hk * wv3;
        }
    }
#pragma unroll
    for (int k = 0; k < INCF; ++k) {
        float wv0 = sw[k * HDIM + 0 * 64 + lane];
        float wv1 = sw[k * HDIM + 1 * 64 + lane];
        float wv2 = sw[k * HDIM + 2 * 64 + lane];
        float wv3 = sw[k * HDIM + 3 * 64 + lane];
#pragma unroll
        for (int j = 0; j < 4; ++j) {
            float nk = nf[j][k];
            a4[j][0] += nk * wv0; a4[j][1] += nk * wv1;
            a4[j][2] += nk * wv2; a4[j][3] += nk * wv3;
        }
    }
#pragma unroll
    for (int j = 0; j < 4; ++j) {
        int node = nbase + j;
#pragma unroll
        for (int j0 = 0; j0 < 4; ++j0) {
            float v = gelu_exact(a4[j][j0]);
            unsigned short h, l;
            split_bf(v, h, l);
            xh[(size_t)node * HDIM + j0 * 64 + lane] = h;
            xl[(size_t)node * HDIM + j0 * 64 + lane] = l;
        }
    }
}

// ---------------- degree / edge-CSR build ----------------
__global__ void count_kernel(const int* __restrict__ dst, int* __restrict__ degi) {
    int e = blockIdx.x * blockDim.x + threadIdx.x;
    if (e < N_EDGES) atomicAdd(&degi[dst[e]], 1);
}

__global__ void dis_kernel(const int* __restrict__ degi, float* __restrict__ dis) {
    int n = blockIdx.x * blockDim.x + threadIdx.x;
    if (n < N_NODES) dis[n] = rsqrtf((float)degi[n] + 1.0f);
}

__global__ __launch_bounds__(1024) void scan_kernel(const int* __restrict__ degi,
                                                    int* __restrict__ off) {
    __shared__ int part[1024];
    int t = threadIdx.x;
    int base = t * 64;
    int s = 0;
    for (int j = 0; j < 64; ++j) s += degi[base + j];
    part[t] = s;
    __syncthreads();
    for (int d = 1; d < 1024; d <<= 1) {
        int v = (t >= d) ? part[t - d] : 0;
        __syncthreads();
        part[t] += v;
        __syncthreads();
    }
    int run = (t == 0) ? 0 : part[t - 1];
    for (int j = 0; j < 64; ++j) {
        off[base + j] = run;
        run += degi[base + j];
    }
    if (t == 1023) off[N_NODES] = run;
}

__global__ void fill_kernel(const int* __restrict__ src, const int* __restrict__ dst,
                            const int* __restrict__ off, int* __restrict__ cursor,
                            int* __restrict__ csr_src) {
    int e = blockIdx.x * blockDim.x + threadIdx.x;
    if (e >= N_EDGES) return;
    int d = dst[e];
    int pos = off[d] + atomicAdd(&cursor[d], 1);
    csr_src[pos] = src[e];
}

// ---------------- weight transpose + bf16 hi/lo ----------------
__global__ __launch_bounds__(256) void wtrans_kernel(const float* __restrict__ w,
                                                     unsigned short* __restrict__ wth,
                                                     unsigned short* __restrict__ wtl_) {
    __shared__ float t[32][257];
    int l = blockIdx.y, kb = blockIdx.x;
    const float* wl = w + (size_t)l * HDIM * HDIM + (size_t)kb * 32 * HDIM;
#pragma unroll
    for (int it = 0; it < 32; ++it) {
        int idx = it * 256 + threadIdx.x;
        t[idx >> 8][idx & 255] = wl[idx];
    }
    __syncthreads();
    unsigned short* wh = wth + (size_t)l * HDIM * HDIM + kb * 32;
    unsigned short* wl2 = wtl_ + (size_t)l * HDIM * HDIM + kb * 32;
    int k = threadIdx.x & 31, n0 = threadIdx.x >> 5;
#pragma unroll
    for (int it = 0; it < 32; ++it) {
        int n = it * 8 + n0;
        unsigned short h, lo;
        split_bf(t[k][n], h, lo);
        wh[(size_t)n * HDIM + k] = h;
        wl2[(size_t)n * HDIM + k] = lo;
    }
}

// ---------------- bf16x3 MFMA GEMM v2: BM=128, BN=256 (full width), prefetch pipeline ----
// Grid: 512 blocks, 8 waves (2M x 4N), wave tile 64x64, BK=32.
// A read ONCE (no bn re-read); next K-step's global loads issued before MFMA phase.
__global__ __launch_bounds__(512) void mfma_gemm_kernel(
    const unsigned short* __restrict__ Ah, const unsigned short* __restrict__ Al,
    const unsigned short* __restrict__ Bh, const unsigned short* __restrict__ Bl,
    float* __restrict__ C_)
{
    __shared__ unsigned short AsH[128 * 32];
    __shared__ unsigned short AsL[128 * 32];
    __shared__ unsigned short BsH[256 * 32];
    __shared__ unsigned short BsL[256 * 32];
    int tid = threadIdx.x;
    int w = tid >> 6, l = tid & 63;
    int bm = blockIdx.x;
    int wm = w >> 2, wn = w & 3;
    int fr = l & 15, fs = l >> 4;

    f32x4 acc[4][4];
#pragma unroll
    for (int m = 0; m < 4; ++m)
#pragma unroll
        for (int n = 0; n < 4; ++n) acc[m][n] = (f32x4){0.f, 0.f, 0.f, 0.f};

    const size_t aoff = (size_t)(bm * 128) * HDIM;
    const int ra = tid >> 2, suba = tid & 3;           // A chunk: 512 chunks of 16B

    uint4 cAh, cAl, cBh[2], cBl[2];
    {
        size_t g = (size_t)ra * HDIM + 0 + suba * 8;
        cAh = *(const uint4*)(Ah + aoff + g);
        cAl = *(const uint4*)(Al + aoff + g);
#pragma unroll
        for (int j = 0; j < 2; ++j) {
            int s = j * 512 + tid;
            int row = s >> 2, sub = s & 3;
            size_t gb = (size_t)row * HDIM + 0 + sub * 8;
            cBh[j] = *(const uint4*)(Bh + gb);
            cBl[j] = *(const uint4*)(Bl + gb);
        }
    }

    for (int k0 = 0; k0 < HDIM; k0 += 32) {
        __syncthreads();   // previous iteration's frag reads complete
        {
            int cl = ra * 4 + (suba ^ ((ra >> 1) & 3));
            *(uint4*)&AsH[cl * 8] = cAh;
            *(uint4*)&AsL[cl * 8] = cAl;
#pragma unroll
            for (int j = 0; j < 2; ++j) {
                int s = j * 512 + tid;
                int row = s >> 2, sub = s & 3;
                int cl2 = row * 4 + (sub ^ ((row >> 1) & 3));
                *(uint4*)&BsH[cl2 * 8] = cBh[j];
                *(uint4*)&BsL[cl2 * 8] = cBl[j];
            }
        }
        __syncthreads();
        // prefetch next K-step while MFMA phase runs below
        if (k0 + 32 < HDIM) {
            size_t g = (size_t)ra * HDIM + (k0 + 32) + suba * 8;
            cAh = *(const uint4*)(Ah + aoff + g);
            cAl = *(const uint4*)(Al + aoff + g);
#pragma unroll
            for (int j = 0; j < 2; ++j) {
                int s = j * 512 + tid;
                int row = s >> 2, sub = s & 3;
                size_t gb = (size_t)row * HDIM + (k0 + 32) + sub * 8;
                cBh[j] = *(const uint4*)(Bh + gb);
                cBl[j] = *(const uint4*)(Bl + gb);
            }
        }

        short8v afh[4], afl[4], bfh[4], bfl[4];
#pragma unroll
        for (int m = 0; m < 4; ++m) {
            int row = wm * 64 + m * 16 + fr;
            int cl = row * 4 + (fs ^ ((row >> 1) & 3));
            afh[m] = *(const short8v*)&AsH[cl * 8];
            afl[m] = *(const short8v*)&AsL[cl * 8];
        }
#pragma unroll
        for (int n = 0; n < 4; ++n) {
            int row = wn * 64 + n * 16 + fr;
            int cl = row * 4 + (fs ^ ((row >> 1) & 3));
            bfh[n] = *(const short8v*)&BsH[cl * 8];
            bfl[n] = *(const short8v*)&BsL[cl * 8];
        }
#pragma unroll
        for (int m = 0; m < 4; ++m)
#pragma unroll
            for (int n = 0; n < 4; ++n) {
                acc[m][n] = __builtin_amdgcn_mfma_f32_16x16x32_bf16(
                    afh[m], bfl[n], acc[m][n], 0, 0, 0);
                acc[m][n] = __builtin_amdgcn_mfma_f32_16x16x32_bf16(
                    afl[m], bfh[n], acc[m][n], 0, 0, 0);
                acc[m][n] = __builtin_amdgcn_mfma_f32_16x16x32_bf16(
                    afh[m], bfh[n], acc[m][n], 0, 0, 0);
            }
    }

    // C/D layout: col = lane&15, row = (lane>>4)*4 + reg   [m89-verified, r5 refcheck'd]
#pragma unroll
    for (int m = 0; m < 4; ++m) {
#pragma unroll
        for (int n = 0; n < 4; ++n) {
            int col = wn * 64 + n * 16 + fr;
#pragma unroll
            for (int r = 0; r < 4; ++r) {
                int rowg = bm * 128 + wm * 64 + m * 16 + fs * 4 + r;
                C_[(size_t)rowg * HDIM + col] = acc[m][n][r];
            }
        }
    }
}

// ---------------- fused aggregate + LN + relu (+residual), 4-deep pipelined gather ----------------
__global__ __launch_bounds__(256) void agg_ln_kernel(
    const float* __restrict__ hi, const float* __restrict__ dis,
    const int* __restrict__ off, const int* __restrict__ csr_src,
    const float* __restrict__ bias, const float* __restrict__ g,
    const float* __restrict__ bln,
    unsigned short* __restrict__ xh, unsigned short* __restrict__ xl,
    int addResidual)
{
    int gtid = blockIdx.x * blockDim.x + threadIdx.x;
    int n = gtid >> 6;
    int lane = threadIdx.x & 63;
    if (n >= N_NODES) return;
    float dn = dis[n];
    int p0 = off[n], p1 = off[n + 1];
    int deg = p1 - p0;
    float4 vself = *(const float4*)(hi + (size_t)n * HDIM + lane * 4);
    float4 bv = *(const float4*)(bias + lane * 4);
    float4 gv = *(const float4*)(g + lane * 4);
    float4 bb = *(const float4*)(bln + lane * 4);

    float4 acc = make_float4(0.f, 0.f, 0.f, 0.f);
    float4 v0, v1, v2, v3;
    float wt0 = 0.f, wt1 = 0.f, wt2 = 0.f, wt3 = 0.f;
    if (deg > 0) { int s = csr_src[p0 + 0]; wt0 = dis[s]; v0 = *(const float4*)(hi + (size_t)s * HDIM + lane * 4); }
    if (deg > 1) { int s = csr_src[p0 + 1]; wt1 = dis[s]; v1 = *(const float4*)(hi + (size_t)s * HDIM + lane * 4); }
    if (deg > 2) { int s = csr_src[p0 + 2]; wt2 = dis[s]; v2 = *(const float4*)(hi + (size_t)s * HDIM + lane * 4); }
    if (deg > 3) { int s = csr_src[p0 + 3]; wt3 = dis[s]; v3 = *(const float4*)(hi + (size_t)s * HDIM + lane * 4); }
    int pp = 0;
    for (; pp + 4 <= deg; pp += 4) {
        float4 v = v0; float wv = wt0 * dn;
        if (pp + 4 < deg) { int s = csr_src[p0 + pp + 4]; wt0 = dis[s]; v0 = *(const float4*)(hi + (size_t)s * HDIM + lane * 4); }
        acc.x += v.x * wv; acc.y += v.y * wv; acc.z += v.z * wv; acc.w += v.w * wv;
        v = v1; wv = wt1 * dn;
        if (pp + 5 < deg) { int s = csr_src[p0 + pp + 5]; wt1 = dis[s]; v1 = *(const float4*)(hi + (size_t)s * HDIM + lane * 4); }
        acc.x += v.x * wv; acc.y += v.y * wv; acc.z += v.z * wv; acc.w += v.w * wv;
        v = v2; wv = wt2 * dn;
        if (pp + 6 < deg) { int s = csr_src[p0 + pp + 6]; wt2 = dis[s]; v2 = *(const float4*)(hi + (size_t)s * HDIM + lane * 4); }
        acc.x += v.x * wv; acc.y += v.y * wv; acc.z += v.z * wv; acc.w += v.w * wv;
        v = v3; wv = wt3 * dn;
        if (pp + 7 < deg) { int s = csr_src[p0 + pp + 7]; wt3 = dis[s]; v3 = *(const float4*)(hi + (size_t)s * HDIM + lane * 4); }
        acc.x += v.x * wv; acc.y += v.y * wv; acc.z += v.z * wv; acc.w += v.w * wv;
    }
    int r = deg - pp;
    if (r > 0) { float wv = wt0 * dn; acc.x += v0.x * wv; acc.y += v0.y * wv; acc.z += v0.z * wv; acc.w += v0.w * wv; }
    if (r > 1) { float wv = wt1 * dn; acc.x += v1.x * wv; acc.y += v1.y * wv; acc.z += v1.z * wv; acc.w += v1.w * wv; }
    if (r > 2) { float wv = wt2 * dn; acc.x += v2.x * wv; acc.y += v2.y * wv; acc.z += v2.z * wv; acc.w += v2.w * wv; }

    {
        float wv = dn * dn;
        acc.x += vself.x * wv + bv.x;
        acc.y += vself.y * wv + bv.y;
        acc.z += vself.z * wv + bv.z;
        acc.w += vself.w * wv + bv.w;
    }
    float s1 = acc.x + acc.y + acc.z + acc.w;
    float s2 = acc.x * acc.x + acc.y * acc.y + acc.z * acc.z + acc.w * acc.w;
#pragma unroll
    for (int m = 1; m < 64; m <<= 1) {
        s1 += __shfl_xor(s1, m);
        s2 += __shfl_xor(s2, m);
    }
    float mu = s1 * (1.0f / 256.0f);
    float var = s2 * (1.0f / 256.0f) - mu * mu;
    float inv = rsqrtf(var + 1e-5f);
    float4 res;
    res.x = fmaxf((acc.x - mu) * inv * gv.x + bb.x, 0.0f);
    res.y = fmaxf((acc.y - mu) * inv * gv.y + bb.y, 0.0f);
    res.z = fmaxf((acc.z - mu) * inv * gv.z + bb.z, 0.0f);
    res.w = fmaxf((acc.w - mu) * inv * gv.w + bb.w, 0.0f);
    if (addResidual) {
        ushort4 oh = *(const ushort4*)(xh + (size_t)n * HDIM + lane * 4);
        ushort4 ol = *(const ushort4*)(xl + (size_t)n * HDIM + lane * 4);
        res.x += bf2f(oh.x) + bf2f(ol.x);
        res.y += bf2f(oh.y) + bf2f(ol.y);
        res.z += bf2f(oh.z) + bf2f(ol.z);
        res.w += bf2f(oh.w) + bf2f(ol.w);
    }
    ushort4 h4, l4;
    split_bf(res.x, h4.x, l4.x);
    split_bf(res.y, h4.y, l4.y);
    split_bf(res.z, h4.z, l4.z);
    split_bf(res.w, h4.w, l4.w);
    *(ushort4*)(xh + (size_t)n * HDIM + lane * 4) = h4;
    *(ushort4*)(xl + (size_t)n * HDIM + lane * 4) = l4;
}

// ---------------- cluster-CSR build + atomic-free pooling ----------------
__global__ void ccount_kernel(const int* __restrict__ cluster, int* __restrict__ ccnt) {
    int n = blockIdx.x * blockDim.x + threadIdx.x;
    if (n < N_NODES) atomicAdd(&ccnt[cluster[n]], 1);
}

__global__ __launch_bounds__(1024) void cscan_kernel(const int* __restrict__ ccnt,
                                                     int* __restrict__ coff) {
    __shared__ int part[1024];
    int t = threadIdx.x;
    int s = 0;
    for (int j = 0; j < 4; ++j) s += ccnt[t * 4 + j];
    part[t] = s;
    __syncthreads();
    for (int d = 1; d < 1024; d <<= 1) {
        int v = (t >= d) ? part[t - d] : 0;
        __syncthreads();
        part[t] += v;
        __syncthreads();
    }
    int run = (t == 0) ? 0 : part[t - 1];
    for (int j = 0; j < 4; ++j) {
        coff[t * 4 + j] = run;
        run += ccnt[t * 4 + j];
    }
    if (t == 1023) coff[NCLUST] = run;
}

__global__ void cfill_kernel(const int* __restrict__ cluster, const int* __restrict__ coff,
                             int* __restrict__ ccur, int* __restrict__ cnodes) {
    int n = blockIdx.x * blockDim.x + threadIdx.x;
    if (n >= N_NODES) return;
    int c = cluster[n];
    cnodes[coff[c] + atomicAdd(&ccur[c], 1)] = n;
}

__global__ __launch_bounds__(256) void pool_csr_kernel(const unsigned short* __restrict__ xh,
                                                       const unsigned short* __restrict__ xl,
                                                       const int* __restrict__ coff,
                                                       const int* __restrict__ cnodes,
                                                       float* __restrict__ pooled) {
    int gtid = blockIdx.x * blockDim.x + threadIdx.x;
    int c = gtid >> 6;
    int lane = threadIdx.x & 63;
    if (c >= NCLUST) return;
    int p0 = coff[c], p1 = coff[c + 1];
    float4 acc = make_float4(0.f, 0.f, 0.f, 0.f);
    for (int p = p0; p < p1; ++p) {
        int n = cnodes[p];
        ushort4 h4 = *(const ushort4*)(xh + (size_t)n * HDIM + lane * 4);
        ushort4 l4 = *(const ushort4*)(xl + (size_t)n * HDIM + lane * 4);
        acc.x += bf2f(h4.x) + bf2f(l4.x);
        acc.y += bf2f(h4.y) + bf2f(l4.y);
        acc.z += bf2f(h4.z) + bf2f(l4.z);
        acc.w += bf2f(h4.w) + bf2f(l4.w);
    }
    float inv = 1.0f / fmaxf((float)(p1 - p0), 1.0f);
    acc.x *= inv; acc.y *= inv; acc.z *= inv; acc.w *= inv;
    *(float4*)(pooled + (size_t)c * HDIM + lane * 4) = acc;
}

__global__ __launch_bounds__(256) void colsq_kernel(const float* __restrict__ pooled,
                                                    float* __restrict__ colsq) {
    int h = threadIdx.x;
    int c0 = blockIdx.x * 16;
    float sq = 0.f;
    for (int cc = 0; cc < 16; ++cc) {
        float v = pooled[(size_t)(c0 + cc) * HDIM + h];
        sq += v * v;
    }
    atomicAdd(&colsq[h], sq);
}

__global__ __launch_bounds__(256) void final_kernel(const float* __restrict__ pooled,
                                                    const float* __restrict__ colsq,
                                                    float* __restrict__ out) {
    int i = blockIdx.x * blockDim.x + threadIdx.x;
    if (i >= NCLUST * HDIM) return;
    int h = i & (HDIM - 1);
    float nrm = fmaxf(sqrtf(colsq[h]), 1e-6f);
    out[i] = pooled[i] / nrm;
}

extern "C" void kernel_launch(void* const* d_in, const int* in_sizes, int n_in,
                              void* d_out, int out_size, void* d_ws, size_t ws_size,
                              hipStream_t stream) {
    const float* x_geo   = (const float*)d_in[0];
    const int*   id_index = (const int*)d_in[1];
    const int*   edge_index = (const int*)d_in[2];
    const int*   cluster = (const int*)d_in[3];
    const float* id_emb  = (const float*)d_in[4];
    const float* enc_w1  = (const float*)d_in[5];
    const float* enc_b1  = (const float*)d_in[6];
    const float* enc_w2  = (const float*)d_in[7];
    const float* enc_b2  = (const float*)d_in[8];
    const float* enc_w3  = (const float*)d_in[9];
    const float* enc_b3  = (const float*)d_in[10];
    const float* skip_w  = (const float*)d_in[11];
    const float* skip_b  = (const float*)d_in[12];
    const float* gcn_w   = (const float*)d_in[13];
    const float* gcn_b   = (const float*)d_in[14];
    const float* ln_g    = (const float*)d_in[15];
    const float* ln_b    = (const float*)d_in[16];
    float* out = (float*)d_out;

    char* ws = (char*)d_ws;
    size_t o = 0;
    auto alloc = [&](size_t bytes) {
        char* p = ws + o;
        o += (bytes + 255) & ~(size_t)255;
        return p;
    };
    float*          hi     = (float*)alloc((size_t)N_NODES * HDIM * 4);
    unsigned short* xh     = (unsigned short*)alloc((size_t)N_NODES * HDIM * 2);
    unsigned short* xl     = (unsigned short*)alloc((size_t)N_NODES * HDIM * 2);
    unsigned short* wth    = (unsigned short*)alloc((size_t)NLAYERS * HDIM * HDIM * 2);
    unsigned short* wtl    = (unsigned short*)alloc((size_t)NLAYERS * HDIM * HDIM * 2);
    int*   degi    = (int*)alloc((size_t)N_NODES * 4);
    float* dis     = (float*)alloc((size_t)N_NODES * 4);
    int*   off     = (int*)alloc((size_t)(N_NODES + 1) * 4);
    int*   cursor  = (int*)alloc((size_t)N_NODES * 4);
    int*   csr_src = (int*)alloc((size_t)N_EDGES * 4);
    int*   ccnt    = (int*)alloc((size_t)NCLUST * 4);
    int*   coff    = (int*)alloc((size_t)(NCLUST + 1) * 4);
    int*   ccur    = (int*)alloc((size_t)NCLUST * 4);
    int*   cnodes  = (int*)alloc((size_t)N_NODES * 4);
    float* pooled  = (float*)alloc((size_t)NCLUST * HDIM * 4);
    float* colsq   = (float*)alloc((size_t)256 * 4);

    const int* esrc = edge_index;
    const int* edst = edge_index + N_EDGES;

    hipMemsetAsync(degi, 0, (size_t)N_NODES * 4, stream);
    hipMemsetAsync(cursor, 0, (size_t)N_NODES * 4, stream);
    hipMemsetAsync(ccnt, 0, (size_t)NCLUST * 4, stream);
    hipMemsetAsync(ccur, 0, (size_t)NCLUST * 4, stream);
    hipMemsetAsync(colsq, 0, (size_t)256 * 4, stream);

    encoder_kernel<<<N_NODES / 16, 256, 0, stream>>>(
        x_geo, id_index, id_emb, enc_w1, enc_b1, enc_w2, enc_b2, enc_w3, enc_b3,
        skip_w, skip_b, xh, xl);

    wtrans_kernel<<<dim3(8, NLAYERS), 256, 0, stream>>>(gcn_w, wth, wtl);

    count_kernel<<<N_EDGES / 256, 256, 0, stream>>>(edst, degi);
    dis_kernel<<<N_NODES / 256, 256, 0, stream>>>(degi, dis);
    scan_kernel<<<1, 1024, 0, stream>>>(degi, off);
    fill_kernel<<<N_EDGES / 256, 256, 0, stream>>>(esrc, edst, off, cursor, csr_src);

    ccount_kernel<<<N_NODES / 256, 256, 0, stream>>>(cluster, ccnt);
    cscan_kernel<<<1, 1024, 0, stream>>>(ccnt, coff);
    cfill_kernel<<<N_NODES / 256, 256, 0, stream>>>(cluster, coff, ccur, cnodes);

    for (int i = 0; i < NLAYERS; ++i) {
        mfma_gemm_kernel<<<N_NODES / 128, 512, 0, stream>>>(
            xh, xl, wth + (size_t)i * HDIM * HDIM, wtl + (size_t)i * HDIM * HDIM, hi);
        agg_ln_kernel<<<N_NODES / 4, 256, 0, stream>>>(
            hi, dis, off, csr_src, gcn_b + (size_t)i * HDIM,
            ln_g + (size_t)i * HDIM, ln_b + (size_t)i * HDIM, xh, xl, (i == 0) ? 1 : 0);
    }

    pool_csr_kernel<<<NCLUST / 4, 256, 0, stream>>>(xh, xl, coff, cnodes, pooled);
    colsq_kernel<<<NCLUST / 16, 256, 0, stream>>>(pooled, colsq);
    final_kernel<<<NCLUST * HDIM / 256, 256, 0, stream>>>(pooled, colsq, out);
}

// Round 13
// 1522.185 us; speedup vs baseline: 1.6874x; 1.1211x over previous
//
#include <hip/hip_runtime.h>
#include <math.h>

#define N_NODES 65536
#define N_EDGES 524288
#define HDIM 256
#define NLAYERS 9
#define NCLUST 4096
#define HQ 64
#define INCF 11

typedef __attribute__((ext_vector_type(8))) short short8v;
typedef __attribute__((ext_vector_type(4))) float f32x4;

__device__ __forceinline__ float gelu_exact(float v) {
    return 0.5f * v * (1.0f + erff(v * 0.70710678118654752440f));
}

__device__ __forceinline__ unsigned short f2bf(float f) {
    union { float f; unsigned u; } a; a.f = f;
    unsigned r = a.u + 0x7FFFu + ((a.u >> 16) & 1u);  // round-nearest-even
    return (unsigned short)(r >> 16);
}

__device__ __forceinline__ float bf2f(unsigned short h) {
    union { unsigned u; float f; } a; a.u = ((unsigned)h) << 16;
    return a.f;
}

__device__ __forceinline__ void split_bf(float v, unsigned short& h, unsigned short& l) {
    h = f2bf(v);
    l = f2bf(v - bf2f(h));
}

// async global->LDS, 16B per lane. LDS dest = wave-uniform base + lane*16;
// global src is per-lane (pre-swizzled).
__device__ __forceinline__ void gload16(const void* g, void* l) {
    __builtin_amdgcn_global_load_lds(
        (const __attribute__((address_space(1))) void*)g,
        (__attribute__((address_space(3))) void*)l,
        16, 0, 0);
}

// ---------------- encoder v2: wave per 4 nodes ----------------
__global__ __launch_bounds__(256) void encoder_kernel(
    const float* __restrict__ x_geo, const int* __restrict__ id_index,
    const float* __restrict__ id_emb,
    const float* __restrict__ w1, const float* __restrict__ b1,
    const float* __restrict__ w2, const float* __restrict__ b2,
    const float* __restrict__ w3, const float* __restrict__ b3,
    const float* __restrict__ sw, const float* __restrict__ sb,
    unsigned short* __restrict__ xh, unsigned short* __restrict__ xl)
{
    int wid = blockIdx.x * 4 + (threadIdx.x >> 6);
    int lane = threadIdx.x & 63;
    int nbase = wid * 4;
    if (nbase >= N_NODES) return;

    float nf[4][INCF];
#pragma unroll
    for (int j = 0; j < 4; ++j) {
        int node = nbase + j;
        nf[j][0] = x_geo[node * 3 + 0];
        nf[j][1] = x_geo[node * 3 + 1];
        nf[j][2] = x_geo[node * 3 + 2];
        int idv = id_index[node];
#pragma unroll
        for (int k = 0; k < 8; ++k) nf[j][3 + k] = id_emb[idv * 8 + k];
    }

    float h1[4];
    {
        float b = b1[lane];
        float a0 = b, a1 = b, a2 = b, a3 = b;
#pragma unroll
        for (int k = 0; k < INCF; ++k) {
            float wv = w1[k * HQ + lane];
            a0 += nf[0][k] * wv; a1 += nf[1][k] * wv;
            a2 += nf[2][k] * wv; a3 += nf[3][k] * wv;
        }
        h1[0] = gelu_exact(a0); h1[1] = gelu_exact(a1);
        h1[2] = gelu_exact(a2); h1[3] = gelu_exact(a3);
    }

    float h2[4];
    {
        float b = b2[lane];
        float a0 = b, a1 = b, a2 = b, a3 = b;
        for (int k = 0; k < HQ; ++k) {
            float wv = w2[k * HQ + lane];
            a0 += __shfl(h1[0], k) * wv; a1 += __shfl(h1[1], k) * wv;
            a2 += __shfl(h1[2], k) * wv; a3 += __shfl(h1[3], k) * wv;
        }
        h2[0] = gelu_exact(a0); h2[1] = gelu_exact(a1);
        h2[2] = gelu_exact(a2); h2[3] = gelu_exact(a3);
    }

    float a4[4][4];
#pragma unroll
    for (int j0 = 0; j0 < 4; ++j0) {
        float b = b3[j0 * 64 + lane] + sb[j0 * 64 + lane];
#pragma unroll
        for (int j = 0; j < 4; ++j) a4[j][j0] = b;
    }
    for (int k = 0; k < HQ; ++k) {
        float wv0 = w3[k * HDIM + 0 * 64 + lane];
        float wv1 = w3[k * HDIM + 1 * 64 + lane];
        float wv2 = w3[k * HDIM + 2 * 64 + lane];
        float wv3 = w3[k * HDIM + 3 * 64 + lane];
#pragma unroll
        for (int j = 0; j < 4; ++j) {
            float hk = __shfl(h2[j], k);
            a4[j][0] += hk * wv0; a4[j][1] += hk * wv1;
            a4[j][2] += hk * wv2; a4[j][3] += hk * wv3;
        }
    }
#pragma unroll
    for (int k = 0; k < INCF; ++k) {
        float wv0 = sw[k * HDIM + 0 * 64 + lane];
        float wv1 = sw[k * HDIM + 1 * 64 + lane];
        float wv2 = sw[k * HDIM + 2 * 64 + lane];
        float wv3 = sw[k * HDIM + 3 * 64 + lane];
#pragma unroll
        for (int j = 0; j < 4; ++j) {
            float nk = nf[j][k];
            a4[j][0] += nk * wv0; a4[j][1] += nk * wv1;
            a4[j][2] += nk * wv2; a4[j][3] += nk * wv3;
        }
    }
#pragma unroll
    for (int j = 0; j < 4; ++j) {
        int node = nbase + j;
#pragma unroll
        for (int j0 = 0; j0 < 4; ++j0) {
            float v = gelu_exact(a4[j][j0]);
            unsigned short h, l;
            split_bf(v, h, l);
            xh[(size_t)node * HDIM + j0 * 64 + lane] = h;
            xl[(size_t)node * HDIM + j0 * 64 + lane] = l;
        }
    }
}

// ---------------- degree / edge-CSR build ----------------
__global__ void count_kernel(const int* __restrict__ dst, int* __restrict__ degi) {
    int e = blockIdx.x * blockDim.x + threadIdx.x;
    if (e < N_EDGES) atomicAdd(&degi[dst[e]], 1);
}

__global__ void dis_kernel(const int* __restrict__ degi, float* __restrict__ dis) {
    int n = blockIdx.x * blockDim.x + threadIdx.x;
    if (n < N_NODES) dis[n] = rsqrtf((float)degi[n] + 1.0f);
}

__global__ __launch_bounds__(1024) void scan_kernel(const int* __restrict__ degi,
                                                    int* __restrict__ off) {
    __shared__ int part[1024];
    int t = threadIdx.x;
    int base = t * 64;
    int s = 0;
    for (int j = 0; j < 64; ++j) s += degi[base + j];
    part[t] = s;
    __syncthreads();
    for (int d = 1; d < 1024; d <<= 1) {
        int v = (t >= d) ? part[t - d] : 0;
        __syncthreads();
        part[t] += v;
        __syncthreads();
    }
    int run = (t == 0) ? 0 : part[t - 1];
    for (int j = 0; j < 64; ++j) {
        off[base + j] = run;
        run += degi[base + j];
    }
    if (t == 1023) off[N_NODES] = run;
}

__global__ void fill_kernel(const int* __restrict__ src, const int* __restrict__ dst,
                            const int* __restrict__ off, int* __restrict__ cursor,
                            int* __restrict__ csr_src) {
    int e = blockIdx.x * blockDim.x + threadIdx.x;
    if (e >= N_EDGES) return;
    int d = dst[e];
    int pos = off[d] + atomicAdd(&cursor[d], 1);
    csr_src[pos] = src[e];
}

// ---------------- weight transpose + bf16 hi/lo ----------------
__global__ __launch_bounds__(256) void wtrans_kernel(const float* __restrict__ w,
                                                     unsigned short* __restrict__ wth,
                                                     unsigned short* __restrict__ wtl_) {
    __shared__ float t[32][257];
    int l = blockIdx.y, kb = blockIdx.x;
    const float* wl = w + (size_t)l * HDIM * HDIM + (size_t)kb * 32 * HDIM;
#pragma unroll
    for (int it = 0; it < 32; ++it) {
        int idx = it * 256 + threadIdx.x;
        t[idx >> 8][idx & 255] = wl[idx];
    }
    __syncthreads();
    unsigned short* wh = wth + (size_t)l * HDIM * HDIM + kb * 32;
    unsigned short* wl2 = wtl_ + (size_t)l * HDIM * HDIM + kb * 32;
    int k = threadIdx.x & 31, n0 = threadIdx.x >> 5;
#pragma unroll
    for (int it = 0; it < 32; ++it) {
        int n = it * 8 + n0;
        unsigned short h, lo;
        split_bf(t[k][n], h, lo);
        wh[(size_t)n * HDIM + k] = h;
        wl2[(size_t)n * HDIM + k] = lo;
    }
}

// ---------------- bf16x3 MFMA GEMM v3: global_load_lds staging (width=16) ----
// BM=128, BN=256, BK=32, 8 waves (2M x 4N). LDS layout LINEAR in chunk index;
// the chunk swizzle (sub ^ ((row>>1)&3)) is applied on the GLOBAL source addr
// (XOR involution within each 64B row-group), ds_read side unchanged (rule #21).
__global__ __launch_bounds__(512) void mfma_gemm_kernel(
    const unsigned short* __restrict__ Ah, const unsigned short* __restrict__ Al,
    const unsigned short* __restrict__ Bh, const unsigned short* __restrict__ Bl,
    float* __restrict__ C_)
{
    __shared__ unsigned short AsH[128 * 32];
    __shared__ unsigned short AsL[128 * 32];
    __shared__ unsigned short BsH[256 * 32];
    __shared__ unsigned short BsL[256 * 32];
    int tid = threadIdx.x;
    int w = tid >> 6, l = tid & 63;
    int bm = blockIdx.x;
    int wm = w >> 2, wn = w & 3;
    int fr = l & 15, fs = l >> 4;

    f32x4 acc[4][4];
#pragma unroll
    for (int m = 0; m < 4; ++m)
#pragma unroll
        for (int n = 0; n < 4; ++n) acc[m][n] = (f32x4){0.f, 0.f, 0.f, 0.f};

    const size_t aoff = (size_t)(bm * 128) * HDIM;
    // A: 512 chunks of 16B (1/thread). B: 1024 chunks (2/thread).
    const int rowA = tid >> 2, subA = tid & 3;
    const int sgA = subA ^ ((rowA >> 1) & 3);          // pre-swizzled global sub-chunk
    const int rowB1 = (512 + tid) >> 2;                // = 128 + rowA
    const int sgB1 = subA ^ ((rowB1 >> 1) & 3);

    unsigned short* lAH = &AsH[(w * 64) * 8];          // wave-uniform LDS bases
    unsigned short* lAL = &AsL[(w * 64) * 8];
    unsigned short* lBH0 = &BsH[(w * 64) * 8];
    unsigned short* lBL0 = &BsL[(w * 64) * 8];
    unsigned short* lBH1 = &BsH[(512 + w * 64) * 8];
    unsigned short* lBL1 = &BsL[(512 + w * 64) * 8];

    for (int k0 = 0; k0 < HDIM; k0 += 32) {
        // stage tile k0: 6 async 16B loads/thread, straight to LDS
        gload16(Ah + aoff + (size_t)rowA * HDIM + k0 + sgA * 8, lAH);
        gload16(Al + aoff + (size_t)rowA * HDIM + k0 + sgA * 8, lAL);
        gload16(Bh + (size_t)rowA * HDIM + k0 + sgA * 8, lBH0);
        gload16(Bl + (size_t)rowA * HDIM + k0 + sgA * 8, lBL0);
        gload16(Bh + (size_t)rowB1 * HDIM + k0 + sgB1 * 8, lBH1);
        gload16(Bl + (size_t)rowB1 * HDIM + k0 + sgB1 * 8, lBL1);
        asm volatile("s_waitcnt vmcnt(0)" ::: "memory");
        __syncthreads();

        short8v afh[4], afl[4], bfh[4], bfl[4];
#pragma unroll
        for (int m = 0; m < 4; ++m) {
            int row = wm * 64 + m * 16 + fr;
            int cl = row * 4 + (fs ^ ((row >> 1) & 3));
            afh[m] = *(const short8v*)&AsH[cl * 8];
            afl[m] = *(const short8v*)&AsL[cl * 8];
        }
#pragma unroll
        for (int n = 0; n < 4; ++n) {
            int row = wn * 64 + n * 16 + fr;
            int cl = row * 4 + (fs ^ ((row >> 1) & 3));
            bfh[n] = *(const short8v*)&BsH[cl * 8];
            bfl[n] = *(const short8v*)&BsL[cl * 8];
        }
#pragma unroll
        for (int m = 0; m < 4; ++m)
#pragma unroll
            for (int n = 0; n < 4; ++n) {
                acc[m][n] = __builtin_amdgcn_mfma_f32_16x16x32_bf16(
                    afh[m], bfl[n], acc[m][n], 0, 0, 0);
                acc[m][n] = __builtin_amdgcn_mfma_f32_16x16x32_bf16(
                    afl[m], bfh[n], acc[m][n], 0, 0, 0);
                acc[m][n] = __builtin_amdgcn_mfma_f32_16x16x32_bf16(
                    afh[m], bfh[n], acc[m][n], 0, 0, 0);
            }
        __syncthreads();   // all frag reads done before next stage overwrites
    }

    // C/D layout: col = lane&15, row = (lane>>4)*4 + reg   [m89-verified, r5 refcheck'd]
#pragma unroll
    for (int m = 0; m < 4; ++m) {
#pragma unroll
        for (int n = 0; n < 4; ++n) {
            int col = wn * 64 + n * 16 + fr;
#pragma unroll
            for (int r = 0; r < 4; ++r) {
                int rowg = bm * 128 + wm * 64 + m * 16 + fs * 4 + r;
                C_[(size_t)rowg * HDIM + col] = acc[m][n][r];
            }
        }
    }
}

// ---------------- fused aggregate + LN + relu (+residual), 4-deep pipelined gather ----------------
__global__ __launch_bounds__(256) void agg_ln_kernel(
    const float* __restrict__ hi, const float* __restrict__ dis,
    const int* __restrict__ off, const int* __restrict__ csr_src,
    const float* __restrict__ bias, const float* __restrict__ g,
    const float* __restrict__ bln,
    unsigned short* __restrict__ xh, unsigned short* __restrict__ xl,
    int addResidual)
{
    int gtid = blockIdx.x * blockDim.x + threadIdx.x;
    int n = gtid >> 6;
    int lane = threadIdx.x & 63;
    if (n >= N_NODES) return;
    float dn = dis[n];
    int p0 = off[n], p1 = off[n + 1];
    int deg = p1 - p0;
    float4 vself = *(const float4*)(hi + (size_t)n * HDIM + lane * 4);
    float4 bv = *(const float4*)(bias + lane * 4);
    float4 gv = *(const float4*)(g + lane * 4);
    float4 bb = *(const float4*)(bln + lane * 4);

    float4 acc = make_float4(0.f, 0.f, 0.f, 0.f);
    float4 v0, v1, v2, v3;
    float wt0 = 0.f, wt1 = 0.f, wt2 = 0.f, wt3 = 0.f;
    if (deg > 0) { int s = csr_src[p0 + 0]; wt0 = dis[s]; v0 = *(const float4*)(hi + (size_t)s * HDIM + lane * 4); }
    if (deg > 1) { int s = csr_src[p0 + 1]; wt1 = dis[s]; v1 = *(const float4*)(hi + (size_t)s * HDIM + lane * 4); }
    if (deg > 2) { int s = csr_src[p0 + 2]; wt2 = dis[s]; v2 = *(const float4*)(hi + (size_t)s * HDIM + lane * 4); }
    if (deg > 3) { int s = csr_src[p0 + 3]; wt3 = dis[s]; v3 = *(const float4*)(hi + (size_t)s * HDIM + lane * 4); }
    int pp = 0;
    for (; pp + 4 <= deg; pp += 4) {
        float4 v = v0; float wv = wt0 * dn;
        if (pp + 4 < deg) { int s = csr_src[p0 + pp + 4]; wt0 = dis[s]; v0 = *(const float4*)(hi + (size_t)s * HDIM + lane * 4); }
        acc.x += v.x * wv; acc.y += v.y * wv; acc.z += v.z * wv; acc.w += v.w * wv;
        v = v1; wv = wt1 * dn;
        if (pp + 5 < deg) { int s = csr_src[p0 + pp + 5]; wt1 = dis[s]; v1 = *(const float4*)(hi + (size_t)s * HDIM + lane * 4); }
        acc.x += v.x * wv; acc.y += v.y * wv; acc.z += v.z * wv; acc.w += v.w * wv;
        v = v2; wv = wt2 * dn;
        if (pp + 6 < deg) { int s = csr_src[p0 + pp + 6]; wt2 = dis[s]; v2 = *(const float4*)(hi + (size_t)s * HDIM + lane * 4); }
        acc.x += v.x * wv; acc.y += v.y * wv; acc.z += v.z * wv; acc.w += v.w * wv;
        v = v3; wv = wt3 * dn;
        if (pp + 7 < deg) { int s = csr_src[p0 + pp + 7]; wt3 = dis[s]; v3 = *(const float4*)(hi + (size_t)s * HDIM + lane * 4); }
        acc.x += v.x * wv; acc.y += v.y * wv; acc.z += v.z * wv; acc.w += v.w * wv;
    }
    int r = deg - pp;
    if (r > 0) { float wv = wt0 * dn; acc.x += v0.x * wv; acc.y += v0.y * wv; acc.z += v0.z * wv; acc.w += v0.w * wv; }
    if (r > 1) { float wv = wt1 * dn; acc.x += v1.x * wv; acc.y += v1.y * wv; acc.z += v1.z * wv; acc.w += v1.w * wv; }
    if (r > 2) { float wv = wt2 * dn; acc.x += v2.x * wv; acc.y += v2.y * wv; acc.z += v2.z * wv; acc.w += v2.w * wv; }

    {
        float wv = dn * dn;
        acc.x += vself.x * wv + bv.x;
        acc.y += vself.y * wv + bv.y;
        acc.z += vself.z * wv + bv.z;
        acc.w += vself.w * wv + bv.w;
    }
    float s1 = acc.x + acc.y + acc.z + acc.w;
    float s2 = acc.x * acc.x + acc.y * acc.y + acc.z * acc.z + acc.w * acc.w;
#pragma unroll
    for (int m = 1; m < 64; m <<= 1) {
        s1 += __shfl_xor(s1, m);
        s2 += __shfl_xor(s2, m);
    }
    float mu = s1 * (1.0f / 256.0f);
    float var = s2 * (1.0f / 256.0f) - mu * mu;
    float inv = rsqrtf(var + 1e-5f);
    float4 res;
    res.x = fmaxf((acc.x - mu) * inv * gv.x + bb.x, 0.0f);
    res.y = fmaxf((acc.y - mu) * inv * gv.y + bb.y, 0.0f);
    res.z = fmaxf((acc.z - mu) * inv * gv.z + bb.z, 0.0f);
    res.w = fmaxf((acc.w - mu) * inv * gv.w + bb.w, 0.0f);
    if (addResidual) {
        ushort4 oh = *(const ushort4*)(xh + (size_t)n * HDIM + lane * 4);
        ushort4 ol = *(const ushort4*)(xl + (size_t)n * HDIM + lane * 4);
        res.x += bf2f(oh.x) + bf2f(ol.x);
        res.y += bf2f(oh.y) + bf2f(ol.y);
        res.z += bf2f(oh.z) + bf2f(ol.z);
        res.w += bf2f(oh.w) + bf2f(ol.w);
    }
    ushort4 h4, l4;
    split_bf(res.x, h4.x, l4.x);
    split_bf(res.y, h4.y, l4.y);
    split_bf(res.z, h4.z, l4.z);
    split_bf(res.w, h4.w, l4.w);
    *(ushort4*)(xh + (size_t)n * HDIM + lane * 4) = h4;
    *(ushort4*)(xl + (size_t)n * HDIM + lane * 4) = l4;
}

// ---------------- cluster-CSR build + atomic-free pooling ----------------
__global__ void ccount_kernel(const int* __restrict__ cluster, int* __restrict__ ccnt) {
    int n = blockIdx.x * blockDim.x + threadIdx.x;
    if (n < N_NODES) atomicAdd(&ccnt[cluster[n]], 1);
}

__global__ __launch_bounds__(1024) void cscan_kernel(const int* __restrict__ ccnt,
                                                     int* __restrict__ coff) {
    __shared__ int part[1024];
    int t = threadIdx.x;
    int s = 0;
    for (int j = 0; j < 4; ++j) s += ccnt[t * 4 + j];
    part[t] = s;
    __syncthreads();
    for (int d = 1; d < 1024; d <<= 1) {
        int v = (t >= d) ? part[t - d] : 0;
        __syncthreads();
        part[t] += v;
        __syncthreads();
    }
    int run = (t == 0) ? 0 : part[t - 1];
    for (int j = 0; j < 4; ++j) {
        coff[t * 4 + j] = run;
        run += ccnt[t * 4 + j];
    }
    if (t == 1023) coff[NCLUST] = run;
}

__global__ void cfill_kernel(const int* __restrict__ cluster, const int* __restrict__ coff,
                             int* __restrict__ ccur, int* __restrict__ cnodes) {
    int n = blockIdx.x * blockDim.x + threadIdx.x;
    if (n >= N_NODES) return;
    int c = cluster[n];
    cnodes[coff[c] + atomicAdd(&ccur[c], 1)] = n;
}

__global__ __launch_bounds__(256) void pool_csr_kernel(const unsigned short* __restrict__ xh,
                                                       const unsigned short* __restrict__ xl,
                                                       const int* __restrict__ coff,
                                                       const int* __restrict__ cnodes,
                                                       float* __restrict__ pooled) {
    int gtid = blockIdx.x * blockDim.x + threadIdx.x;
    int c = gtid >> 6;
    int lane = threadIdx.x & 63;
    if (c >= NCLUST) return;
    int p0 = coff[c], p1 = coff[c + 1];
    float4 acc = make_float4(0.f, 0.f, 0.f, 0.f);
    for (int p = p0; p < p1; ++p) {
        int n = cnodes[p];
        ushort4 h4 = *(const ushort4*)(xh + (size_t)n * HDIM + lane * 4);
        ushort4 l4 = *(const ushort4*)(xl + (size_t)n * HDIM + lane * 4);
        acc.x += bf2f(h4.x) + bf2f(l4.x);
        acc.y += bf2f(h4.y) + bf2f(l4.y);
        acc.z += bf2f(h4.z) + bf2f(l4.z);
        acc.w += bf2f(h4.w) + bf2f(l4.w);
    }
    float inv = 1.0f / fmaxf((float)(p1 - p0), 1.0f);
    acc.x *= inv; acc.y *= inv; acc.z *= inv; acc.w *= inv;
    *(float4*)(pooled + (size_t)c * HDIM + lane * 4) = acc;
}

__global__ __launch_bounds__(256) void colsq_kernel(const float* __restrict__ pooled,
                                                    float* __restrict__ colsq) {
    int h = threadIdx.x;
    int c0 = blockIdx.x * 16;
    float sq = 0.f;
    for (int cc = 0; cc < 16; ++cc) {
        float v = pooled[(size_t)(c0 + cc) * HDIM + h];
        sq += v * v;
    }
    atomicAdd(&colsq[h], sq);
}

__global__ __launch_bounds__(256) void final_kernel(const float* __restrict__ pooled,
                                                    const float* __restrict__ colsq,
                                                    float* __restrict__ out) {
    int i = blockIdx.x * blockDim.x + threadIdx.x;
    if (i >= NCLUST * HDIM) return;
    int h = i & (HDIM - 1);
    float nrm = fmaxf(sqrtf(colsq[h]), 1e-6f);
    out[i] = pooled[i] / nrm;
}

extern "C" void kernel_launch(void* const* d_in, const int* in_sizes, int n_in,
                              void* d_out, int out_size, void* d_ws, size_t ws_size,
                              hipStream_t stream) {
    const float* x_geo   = (const float*)d_in[0];
    const int*   id_index = (const int*)d_in[1];
    const int*   edge_index = (const int*)d_in[2];
    const int*   cluster = (const int*)d_in[3];
    const float* id_emb  = (const float*)d_in[4];
    const float* enc_w1  = (const float*)d_in[5];
    const float* enc_b1  = (const float*)d_in[6];
    const float* enc_w2  = (const float*)d_in[7];
    const float* enc_b2  = (const float*)d_in[8];
    const float* enc_w3  = (const float*)d_in[9];
    const float* enc_b3  = (const float*)d_in[10];
    const float* skip_w  = (const float*)d_in[11];
    const float* skip_b  = (const float*)d_in[12];
    const float* gcn_w   = (const float*)d_in[13];
    const float* gcn_b   = (const float*)d_in[14];
    const float* ln_g    = (const float*)d_in[15];
    const float* ln_b    = (const float*)d_in[16];
    float* out = (float*)d_out;

    char* ws = (char*)d_ws;
    size_t o = 0;
    auto alloc = [&](size_t bytes) {
        char* p = ws + o;
        o += (bytes + 255) & ~(size_t)255;
        return p;
    };
    float*          hi     = (float*)alloc((size_t)N_NODES * HDIM * 4);
    unsigned short* xh     = (unsigned short*)alloc((size_t)N_NODES * HDIM * 2);
    unsigned short* xl     = (unsigned short*)alloc((size_t)N_NODES * HDIM * 2);
    unsigned short* wth    = (unsigned short*)alloc((size_t)NLAYERS * HDIM * HDIM * 2);
    unsigned short* wtl    = (unsigned short*)alloc((size_t)NLAYERS * HDIM * HDIM * 2);
    int*   degi    = (int*)alloc((size_t)N_NODES * 4);
    float* dis     = (float*)alloc((size_t)N_NODES * 4);
    int*   off     = (int*)alloc((size_t)(N_NODES + 1) * 4);
    int*   cursor  = (int*)alloc((size_t)N_NODES * 4);
    int*   csr_src = (int*)alloc((size_t)N_EDGES * 4);
    int*   ccnt    = (int*)alloc((size_t)NCLUST * 4);
    int*   coff    = (int*)alloc((size_t)(NCLUST + 1) * 4);
    int*   ccur    = (int*)alloc((size_t)NCLUST * 4);
    int*   cnodes  = (int*)alloc((size_t)N_NODES * 4);
    float* pooled  = (float*)alloc((size_t)NCLUST * HDIM * 4);
    float* colsq   = (float*)alloc((size_t)256 * 4);

    const int* esrc = edge_index;
    const int* edst = edge_index + N_EDGES;

    hipMemsetAsync(degi, 0, (size_t)N_NODES * 4, stream);
    hipMemsetAsync(cursor, 0, (size_t)N_NODES * 4, stream);
    hipMemsetAsync(ccnt, 0, (size_t)NCLUST * 4, stream);
    hipMemsetAsync(ccur, 0, (size_t)NCLUST * 4, stream);
    hipMemsetAsync(colsq, 0, (size_t)256 * 4, stream);

    encoder_kernel<<<N_NODES / 16, 256, 0, stream>>>(
        x_geo, id_index, id_emb, enc_w1, enc_b1, enc_w2, enc_b2, enc_w3, enc_b3,
        skip_w, skip_b, xh, xl);

    wtrans_kernel<<<dim3(8, NLAYERS), 256, 0, stream>>>(gcn_w, wth, wtl);

    count_kernel<<<N_EDGES / 256, 256, 0, stream>>>(edst, degi);
    dis_kernel<<<N_NODES / 256, 256, 0, stream>>>(degi, dis);
    scan_kernel<<<1, 1024, 0, stream>>>(degi, off);
    fill_kernel<<<N_EDGES / 256, 256, 0, stream>>>(esrc, edst, off, cursor, csr_src);

    ccount_kernel<<<N_NODES / 256, 256, 0, stream>>>(cluster, ccnt);
    cscan_kernel<<<1, 1024, 0, stream>>>(ccnt, coff);
    cfill_kernel<<<N_NODES / 256, 256, 0, stream>>>(cluster, coff, ccur, cnodes);

    for (int i = 0; i < NLAYERS; ++i) {
        mfma_gemm_kernel<<<N_NODES / 128, 512, 0, stream>>>(
            xh, xl, wth + (size_t)i * HDIM * HDIM, wtl + (size_t)i * HDIM * HDIM, hi);
        agg_ln_kernel<<<N_NODES / 4, 256, 0, stream>>>(
            hi, dis, off, csr_src, gcn_b + (size_t)i * HDIM,
            ln_g + (size_t)i * HDIM, ln_b + (size_t)i * HDIM, xh, xl, (i == 0) ? 1 : 0);
    }

    pool_csr_kernel<<<NCLUST / 4, 256, 0, stream>>>(xh, xl, coff, cnodes, pooled);
    colsq_kernel<<<NCLUST / 16, 256, 0, stream>>>(pooled, colsq);
    final_kernel<<<NCLUST * HDIM / 256, 256, 0, stream>>>(pooled, colsq, out);
}

// Round 14
// 1515.024 us; speedup vs baseline: 1.6953x; 1.0047x over previous
//
#include <hip/hip_runtime.h>
#include <math.h>

#define N_NODES 65536
#define N_EDGES 524288
#define HDIM 256
#define NLAYERS 9
#define NCLUST 4096
#define HQ 64
#define INCF 11

typedef __attribute__((ext_vector_type(8))) short short8v;
typedef __attribute__((ext_vector_type(4))) float f32x4;

__device__ __forceinline__ float gelu_exact(float v) {
    return 0.5f * v * (1.0f + erff(v * 0.70710678118654752440f));
}

__device__ __forceinline__ unsigned short f2bf(float f) {
    union { float f; unsigned u; } a; a.f = f;
    unsigned r = a.u + 0x7FFFu + ((a.u >> 16) & 1u);  // round-nearest-even
    return (unsigned short)(r >> 16);
}

__device__ __forceinline__ float bf2f(unsigned short h) {
    union { unsigned u; float f; } a; a.u = ((unsigned)h) << 16;
    return a.f;
}

__device__ __forceinline__ void split_bf(float v, unsigned short& h, unsigned short& l) {
    h = f2bf(v);
    l = f2bf(v - bf2f(h));
}

// async global->LDS, 16B per lane. LDS dest = wave-uniform base + lane*16;
// global src is per-lane (pre-swizzled).
__device__ __forceinline__ void gload16(const void* g, void* l) {
    __builtin_amdgcn_global_load_lds(
        (const __attribute__((address_space(1))) void*)g,
        (__attribute__((address_space(3))) void*)l,
        16, 0, 0);
}

// ---------------- encoder v2: wave per 4 nodes ----------------
__global__ __launch_bounds__(256) void encoder_kernel(
    const float* __restrict__ x_geo, const int* __restrict__ id_index,
    const float* __restrict__ id_emb,
    const float* __restrict__ w1, const float* __restrict__ b1,
    const float* __restrict__ w2, const float* __restrict__ b2,
    const float* __restrict__ w3, const float* __restrict__ b3,
    const float* __restrict__ sw, const float* __restrict__ sb,
    unsigned short* __restrict__ xh, unsigned short* __restrict__ xl)
{
    int wid = blockIdx.x * 4 + (threadIdx.x >> 6);
    int lane = threadIdx.x & 63;
    int nbase = wid * 4;
    if (nbase >= N_NODES) return;

    float nf[4][INCF];
#pragma unroll
    for (int j = 0; j < 4; ++j) {
        int node = nbase + j;
        nf[j][0] = x_geo[node * 3 + 0];
        nf[j][1] = x_geo[node * 3 + 1];
        nf[j][2] = x_geo[node * 3 + 2];
        int idv = id_index[node];
#pragma unroll
        for (int k = 0; k < 8; ++k) nf[j][3 + k] = id_emb[idv * 8 + k];
    }

    float h1[4];
    {
        float b = b1[lane];
        float a0 = b, a1 = b, a2 = b, a3 = b;
#pragma unroll
        for (int k = 0; k < INCF; ++k) {
            float wv = w1[k * HQ + lane];
            a0 += nf[0][k] * wv; a1 += nf[1][k] * wv;
            a2 += nf[2][k] * wv; a3 += nf[3][k] * wv;
        }
        h1[0] = gelu_exact(a0); h1[1] = gelu_exact(a1);
        h1[2] = gelu_exact(a2); h1[3] = gelu_exact(a3);
    }

    float h2[4];
    {
        float b = b2[lane];
        float a0 = b, a1 = b, a2 = b, a3 = b;
        for (int k = 0; k < HQ; ++k) {
            float wv = w2[k * HQ + lane];
            a0 += __shfl(h1[0], k) * wv; a1 += __shfl(h1[1], k) * wv;
            a2 += __shfl(h1[2], k) * wv; a3 += __shfl(h1[3], k) * wv;
        }
        h2[0] = gelu_exact(a0); h2[1] = gelu_exact(a1);
        h2[2] = gelu_exact(a2); h2[3] = gelu_exact(a3);
    }

    float a4[4][4];
#pragma unroll
    for (int j0 = 0; j0 < 4; ++j0) {
        float b = b3[j0 * 64 + lane] + sb[j0 * 64 + lane];
#pragma unroll
        for (int j = 0; j < 4; ++j) a4[j][j0] = b;
    }
    for (int k = 0; k < HQ; ++k) {
        float wv0 = w3[k * HDIM + 0 * 64 + lane];
        float wv1 = w3[k * HDIM + 1 * 64 + lane];
        float wv2 = w3[k * HDIM + 2 * 64 + lane];
        float wv3 = w3[k * HDIM + 3 * 64 + lane];
#pragma unroll
        for (int j = 0; j < 4; ++j) {
            float hk = __shfl(h2[j], k);
            a4[j][0] += hk * wv0; a4[j][1] += hk * wv1;
            a4[j][2] += hk * wv2; a4[j][3] += hk * wv3;
        }
    }
#pragma unroll
    for (int k = 0; k < INCF; ++k) {
        float wv0 = sw[k * HDIM + 0 * 64 + lane];
        float wv1 = sw[k * HDIM + 1 * 64 + lane];
        float wv2 = sw[k * HDIM + 2 * 64 + lane];
        float wv3 = sw[k * HDIM + 3 * 64 + lane];
#pragma unroll
        for (int j = 0; j < 4; ++j) {
            float nk = nf[j][k];
            a4[j][0] += nk * wv0; a4[j][1] += nk * wv1;
            a4[j][2] += nk * wv2; a4[j][3] += nk * wv3;
        }
    }
#pragma unroll
    for (int j = 0; j < 4; ++j) {
        int node = nbase + j;
#pragma unroll
        for (int j0 = 0; j0 < 4; ++j0) {
            float v = gelu_exact(a4[j][j0]);
            unsigned short h, l;
            split_bf(v, h, l);
            xh[(size_t)node * HDIM + j0 * 64 + lane] = h;
            xl[(size_t)node * HDIM + j0 * 64 + lane] = l;
        }
    }
}

// ---------------- degree / edge-CSR build ----------------
__global__ void count_kernel(const int* __restrict__ dst, int* __restrict__ degi) {
    int e = blockIdx.x * blockDim.x + threadIdx.x;
    if (e < N_EDGES) atomicAdd(&degi[dst[e]], 1);
}

__global__ void dis_kernel(const int* __restrict__ degi, float* __restrict__ dis) {
    int n = blockIdx.x * blockDim.x + threadIdx.x;
    if (n < N_NODES) dis[n] = rsqrtf((float)degi[n] + 1.0f);
}

__global__ __launch_bounds__(1024) void scan_kernel(const int* __restrict__ degi,
                                                    int* __restrict__ off) {
    __shared__ int part[1024];
    int t = threadIdx.x;
    int base = t * 64;
    int s = 0;
    for (int j = 0; j < 64; ++j) s += degi[base + j];
    part[t] = s;
    __syncthreads();
    for (int d = 1; d < 1024; d <<= 1) {
        int v = (t >= d) ? part[t - d] : 0;
        __syncthreads();
        part[t] += v;
        __syncthreads();
    }
    int run = (t == 0) ? 0 : part[t - 1];
    for (int j = 0; j < 64; ++j) {
        off[base + j] = run;
        run += degi[base + j];
    }
    if (t == 1023) off[N_NODES] = run;
}

__global__ void fill_kernel(const int* __restrict__ src, const int* __restrict__ dst,
                            const int* __restrict__ off, int* __restrict__ cursor,
                            int* __restrict__ csr_src) {
    int e = blockIdx.x * blockDim.x + threadIdx.x;
    if (e >= N_EDGES) return;
    int d = dst[e];
    int pos = off[d] + atomicAdd(&cursor[d], 1);
    csr_src[pos] = src[e];
}

// ---------------- weight transpose + bf16 hi/lo ----------------
__global__ __launch_bounds__(256) void wtrans_kernel(const float* __restrict__ w,
                                                     unsigned short* __restrict__ wth,
                                                     unsigned short* __restrict__ wtl_) {
    __shared__ float t[32][257];
    int l = blockIdx.y, kb = blockIdx.x;
    const float* wl = w + (size_t)l * HDIM * HDIM + (size_t)kb * 32 * HDIM;
#pragma unroll
    for (int it = 0; it < 32; ++it) {
        int idx = it * 256 + threadIdx.x;
        t[idx >> 8][idx & 255] = wl[idx];
    }
    __syncthreads();
    unsigned short* wh = wth + (size_t)l * HDIM * HDIM + kb * 32;
    unsigned short* wl2 = wtl_ + (size_t)l * HDIM * HDIM + kb * 32;
    int k = threadIdx.x & 31, n0 = threadIdx.x >> 5;
#pragma unroll
    for (int it = 0; it < 32; ++it) {
        int n = it * 8 + n0;
        unsigned short h, lo;
        split_bf(t[k][n], h, lo);
        wh[(size_t)n * HDIM + k] = h;
        wl2[(size_t)n * HDIM + k] = lo;
    }
}

// ---------------- bf16x3 MFMA GEMM v4: double-buffered gload_lds, counted vmcnt ----
// BM=128, BN=256, BK=32, 8 waves. LDS 2x48KB ping-pong; per K-step:
// STAGE(t+1, other) -> vmcnt(6) [t's 6 loads done, t+1's in flight] ->
// barrier -> ds_read+MFMA(t) -> barrier [t's buf safe to overwrite at t+1].
// Swizzle on GLOBAL source (rule #21), frag-read XOR cancels it (bit-exact v3).
__global__ __launch_bounds__(512) void mfma_gemm_kernel(
    const unsigned short* __restrict__ Ah, const unsigned short* __restrict__ Al,
    const unsigned short* __restrict__ Bh, const unsigned short* __restrict__ Bl,
    float* __restrict__ C_)
{
    __shared__ unsigned short AsH[2][128 * 32];
    __shared__ unsigned short AsL[2][128 * 32];
    __shared__ unsigned short BsH[2][256 * 32];
    __shared__ unsigned short BsL[2][256 * 32];
    int tid = threadIdx.x;
    int w = tid >> 6, l = tid & 63;
    int bm = blockIdx.x;
    int wm = w >> 2, wn = w & 3;
    int fr = l & 15, fs = l >> 4;

    f32x4 acc[4][4];
#pragma unroll
    for (int m = 0; m < 4; ++m)
#pragma unroll
        for (int n = 0; n < 4; ++n) acc[m][n] = (f32x4){0.f, 0.f, 0.f, 0.f};

    const size_t aoff = (size_t)(bm * 128) * HDIM;
    const int rowA = tid >> 2, subA = tid & 3;
    const int sgA = subA ^ ((rowA >> 1) & 3);          // pre-swizzled global sub-chunk
    const int rowB1 = (512 + tid) >> 2;                // = 128 + rowA
    const int sgB1 = subA ^ ((rowB1 >> 1) & 3);
    const int ldsOff = (w * 64) * 8;                   // wave-uniform LDS offset

    // stage K-tile k0 into buffer b (6 async 16B loads/thread)
    auto STAGE = [&](int b, int k0) {
        gload16(Ah + aoff + (size_t)rowA * HDIM + k0 + sgA * 8, &AsH[b][ldsOff]);
        gload16(Al + aoff + (size_t)rowA * HDIM + k0 + sgA * 8, &AsL[b][ldsOff]);
        gload16(Bh + (size_t)rowA * HDIM + k0 + sgA * 8, &BsH[b][ldsOff]);
        gload16(Bl + (size_t)rowA * HDIM + k0 + sgA * 8, &BsL[b][ldsOff]);
        gload16(Bh + (size_t)rowB1 * HDIM + k0 + sgB1 * 8, &BsH[b][4096 + ldsOff]);
        gload16(Bl + (size_t)rowB1 * HDIM + k0 + sgB1 * 8, &BsL[b][4096 + ldsOff]);
    };

    STAGE(0, 0);
#pragma unroll
    for (int t = 0; t < 8; ++t) {
        const int cur = t & 1;
        if (t < 7) {
            STAGE(cur ^ 1, (t + 1) * 32);
            asm volatile("s_waitcnt vmcnt(6)" ::: "memory");
        } else {
            asm volatile("s_waitcnt vmcnt(0)" ::: "memory");
        }
        __syncthreads();   // all waves' tile-t loads landed in LDS

        short8v afh[4], afl[4], bfh[4], bfl[4];
#pragma unroll
        for (int m = 0; m < 4; ++m) {
            int row = wm * 64 + m * 16 + fr;
            int cl = row * 4 + (fs ^ ((row >> 1) & 3));
            afh[m] = *(const short8v*)&AsH[cur][cl * 8];
            afl[m] = *(const short8v*)&AsL[cur][cl * 8];
        }
#pragma unroll
        for (int n = 0; n < 4; ++n) {
            int row = wn * 64 + n * 16 + fr;
            int cl = row * 4 + (fs ^ ((row >> 1) & 3));
            bfh[n] = *(const short8v*)&BsH[cur][cl * 8];
            bfl[n] = *(const short8v*)&BsL[cur][cl * 8];
        }
#pragma unroll
        for (int m = 0; m < 4; ++m)
#pragma unroll
            for (int n = 0; n < 4; ++n) {
                acc[m][n] = __builtin_amdgcn_mfma_f32_16x16x32_bf16(
                    afh[m], bfl[n], acc[m][n], 0, 0, 0);
                acc[m][n] = __builtin_amdgcn_mfma_f32_16x16x32_bf16(
                    afl[m], bfh[n], acc[m][n], 0, 0, 0);
                acc[m][n] = __builtin_amdgcn_mfma_f32_16x16x32_bf16(
                    afh[m], bfh[n], acc[m][n], 0, 0, 0);
            }
        __syncthreads();   // reads of buf[cur] done -> safe to overwrite next iter
    }

    // C/D layout: col = lane&15, row = (lane>>4)*4 + reg   [m89-verified, r5 refcheck'd]
#pragma unroll
    for (int m = 0; m < 4; ++m) {
#pragma unroll
        for (int n = 0; n < 4; ++n) {
            int col = wn * 64 + n * 16 + fr;
#pragma unroll
            for (int r = 0; r < 4; ++r) {
                int rowg = bm * 128 + wm * 64 + m * 16 + fs * 4 + r;
                C_[(size_t)rowg * HDIM + col] = acc[m][n][r];
            }
        }
    }
}

// ---------------- fused aggregate + LN + relu (+residual), 4-deep pipelined gather ----------------
__global__ __launch_bounds__(256) void agg_ln_kernel(
    const float* __restrict__ hi, const float* __restrict__ dis,
    const int* __restrict__ off, const int* __restrict__ csr_src,
    const float* __restrict__ bias, const float* __restrict__ g,
    const float* __restrict__ bln,
    unsigned short* __restrict__ xh, unsigned short* __restrict__ xl,
    int addResidual)
{
    int gtid = blockIdx.x * blockDim.x + threadIdx.x;
    int n = gtid >> 6;
    int lane = threadIdx.x & 63;
    if (n >= N_NODES) return;
    float dn = dis[n];
    int p0 = off[n], p1 = off[n + 1];
    int deg = p1 - p0;
    float4 vself = *(const float4*)(hi + (size_t)n * HDIM + lane * 4);
    float4 bv = *(const float4*)(bias + lane * 4);
    float4 gv = *(const float4*)(g + lane * 4);
    float4 bb = *(const float4*)(bln + lane * 4);

    float4 acc = make_float4(0.f, 0.f, 0.f, 0.f);
    float4 v0, v1, v2, v3;
    float wt0 = 0.f, wt1 = 0.f, wt2 = 0.f, wt3 = 0.f;
    if (deg > 0) { int s = csr_src[p0 + 0]; wt0 = dis[s]; v0 = *(const float4*)(hi + (size_t)s * HDIM + lane * 4); }
    if (deg > 1) { int s = csr_src[p0 + 1]; wt1 = dis[s]; v1 = *(const float4*)(hi + (size_t)s * HDIM + lane * 4); }
    if (deg > 2) { int s = csr_src[p0 + 2]; wt2 = dis[s]; v2 = *(const float4*)(hi + (size_t)s * HDIM + lane * 4); }
    if (deg > 3) { int s = csr_src[p0 + 3]; wt3 = dis[s]; v3 = *(const float4*)(hi + (size_t)s * HDIM + lane * 4); }
    int pp = 0;
    for (; pp + 4 <= deg; pp += 4) {
        float4 v = v0; float wv = wt0 * dn;
        if (pp + 4 < deg) { int s = csr_src[p0 + pp + 4]; wt0 = dis[s]; v0 = *(const float4*)(hi + (size_t)s * HDIM + lane * 4); }
        acc.x += v.x * wv; acc.y += v.y * wv; acc.z += v.z * wv; acc.w += v.w * wv;
        v = v1; wv = wt1 * dn;
        if (pp + 5 < deg) { int s = csr_src[p0 + pp + 5]; wt1 = dis[s]; v1 = *(const float4*)(hi + (size_t)s * HDIM + lane * 4); }
        acc.x += v.x * wv; acc.y += v.y * wv; acc.z += v.z * wv; acc.w += v.w * wv;
        v = v2; wv = wt2 * dn;
        if (pp + 6 < deg) { int s = csr_src[p0 + pp + 6]; wt2 = dis[s]; v2 = *(const float4*)(hi + (size_t)s * HDIM + lane * 4); }
        acc.x += v.x * wv; acc.y += v.y * wv; acc.z += v.z * wv; acc.w += v.w * wv;
        v = v3; wv = wt3 * dn;
        if (pp + 7 < deg) { int s = csr_src[p0 + pp + 7]; wt3 = dis[s]; v3 = *(const float4*)(hi + (size_t)s * HDIM + lane * 4); }
        acc.x += v.x * wv; acc.y += v.y * wv; acc.z += v.z * wv; acc.w += v.w * wv;
    }
    int r = deg - pp;
    if (r > 0) { float wv = wt0 * dn; acc.x += v0.x * wv; acc.y += v0.y * wv; acc.z += v0.z * wv; acc.w += v0.w * wv; }
    if (r > 1) { float wv = wt1 * dn; acc.x += v1.x * wv; acc.y += v1.y * wv; acc.z += v1.z * wv; acc.w += v1.w * wv; }
    if (r > 2) { float wv = wt2 * dn; acc.x += v2.x * wv; acc.y += v2.y * wv; acc.z += v2.z * wv; acc.w += v2.w * wv; }

    {
        float wv = dn * dn;
        acc.x += vself.x * wv + bv.x;
        acc.y += vself.y * wv + bv.y;
        acc.z += vself.z * wv + bv.z;
        acc.w += vself.w * wv + bv.w;
    }
    float s1 = acc.x + acc.y + acc.z + acc.w;
    float s2 = acc.x * acc.x + acc.y * acc.y + acc.z * acc.z + acc.w * acc.w;
#pragma unroll
    for (int m = 1; m < 64; m <<= 1) {
        s1 += __shfl_xor(s1, m);
        s2 += __shfl_xor(s2, m);
    }
    float mu = s1 * (1.0f / 256.0f);
    float var = s2 * (1.0f / 256.0f) - mu * mu;
    float inv = rsqrtf(var + 1e-5f);
    float4 res;
    res.x = fmaxf((acc.x - mu) * inv * gv.x + bb.x, 0.0f);
    res.y = fmaxf((acc.y - mu) * inv * gv.y + bb.y, 0.0f);
    res.z = fmaxf((acc.z - mu) * inv * gv.z + bb.z, 0.0f);
    res.w = fmaxf((acc.w - mu) * inv * gv.w + bb.w, 0.0f);
    if (addResidual) {
        ushort4 oh = *(const ushort4*)(xh + (size_t)n * HDIM + lane * 4);
        ushort4 ol = *(const ushort4*)(xl + (size_t)n * HDIM + lane * 4);
        res.x += bf2f(oh.x) + bf2f(ol.x);
        res.y += bf2f(oh.y) + bf2f(ol.y);
        res.z += bf2f(oh.z) + bf2f(ol.z);
        res.w += bf2f(oh.w) + bf2f(ol.w);
    }
    ushort4 h4, l4;
    split_bf(res.x, h4.x, l4.x);
    split_bf(res.y, h4.y, l4.y);
    split_bf(res.z, h4.z, l4.z);
    split_bf(res.w, h4.w, l4.w);
    *(ushort4*)(xh + (size_t)n * HDIM + lane * 4) = h4;
    *(ushort4*)(xl + (size_t)n * HDIM + lane * 4) = l4;
}

// ---------------- cluster-CSR build + atomic-free pooling ----------------
__global__ void ccount_kernel(const int* __restrict__ cluster, int* __restrict__ ccnt) {
    int n = blockIdx.x * blockDim.x + threadIdx.x;
    if (n < N_NODES) atomicAdd(&ccnt[cluster[n]], 1);
}

__global__ __launch_bounds__(1024) void cscan_kernel(const int* __restrict__ ccnt,
                                                     int* __restrict__ coff) {
    __shared__ int part[1024];
    int t = threadIdx.x;
    int s = 0;
    for (int j = 0; j < 4; ++j) s += ccnt[t * 4 + j];
    part[t] = s;
    __syncthreads();
    for (int d = 1; d < 1024; d <<= 1) {
        int v = (t >= d) ? part[t - d] : 0;
        __syncthreads();
        part[t] += v;
        __syncthreads();
    }
    int run = (t == 0) ? 0 : part[t - 1];
    for (int j = 0; j < 4; ++j) {
        coff[t * 4 + j] = run;
        run += ccnt[t * 4 + j];
    }
    if (t == 1023) coff[NCLUST] = run;
}

__global__ void cfill_kernel(const int* __restrict__ cluster, const int* __restrict__ coff,
                             int* __restrict__ ccur, int* __restrict__ cnodes) {
    int n = blockIdx.x * blockDim.x + threadIdx.x;
    if (n >= N_NODES) return;
    int c = cluster[n];
    cnodes[coff[c] + atomicAdd(&ccur[c], 1)] = n;
}

__global__ __launch_bounds__(256) void pool_csr_kernel(const unsigned short* __restrict__ xh,
                                                       const unsigned short* __restrict__ xl,
                                                       const int* __restrict__ coff,
                                                       const int* __restrict__ cnodes,
                                                       float* __restrict__ pooled) {
    int gtid = blockIdx.x * blockDim.x + threadIdx.x;
    int c = gtid >> 6;
    int lane = threadIdx.x & 63;
    if (c >= NCLUST) return;
    int p0 = coff[c], p1 = coff[c + 1];
    float4 acc = make_float4(0.f, 0.f, 0.f, 0.f);
    for (int p = p0; p < p1; ++p) {
        int n = cnodes[p];
        ushort4 h4 = *(const ushort4*)(xh + (size_t)n * HDIM + lane * 4);
        ushort4 l4 = *(const ushort4*)(xl + (size_t)n * HDIM + lane * 4);
        acc.x += bf2f(h4.x) + bf2f(l4.x);
        acc.y += bf2f(h4.y) + bf2f(l4.y);
        acc.z += bf2f(h4.z) + bf2f(l4.z);
        acc.w += bf2f(h4.w) + bf2f(l4.w);
    }
    float inv = 1.0f / fmaxf((float)(p1 - p0), 1.0f);
    acc.x *= inv; acc.y *= inv; acc.z *= inv; acc.w *= inv;
    *(float4*)(pooled + (size_t)c * HDIM + lane * 4) = acc;
}

__global__ __launch_bounds__(256) void colsq_kernel(const float* __restrict__ pooled,
                                                    float* __restrict__ colsq) {
    int h = threadIdx.x;
    int c0 = blockIdx.x * 16;
    float sq = 0.f;
    for (int cc = 0; cc < 16; ++cc) {
        float v = pooled[(size_t)(c0 + cc) * HDIM + h];
        sq += v * v;
    }
    atomicAdd(&colsq[h], sq);
}

__global__ __launch_bounds__(256) void final_kernel(const float* __restrict__ pooled,
                                                    const float* __restrict__ colsq,
                                                    float* __restrict__ out) {
    int i = blockIdx.x * blockDim.x + threadIdx.x;
    if (i >= NCLUST * HDIM) return;
    int h = i & (HDIM - 1);
    float nrm = fmaxf(sqrtf(colsq[h]), 1e-6f);
    out[i] = pooled[i] / nrm;
}

extern "C" void kernel_launch(void* const* d_in, const int* in_sizes, int n_in,
                              void* d_out, int out_size, void* d_ws, size_t ws_size,
                              hipStream_t stream) {
    const float* x_geo   = (const float*)d_in[0];
    const int*   id_index = (const int*)d_in[1];
    const int*   edge_index = (const int*)d_in[2];
    const int*   cluster = (const int*)d_in[3];
    const float* id_emb  = (const float*)d_in[4];
    const float* enc_w1  = (const float*)d_in[5];
    const float* enc_b1  = (const float*)d_in[6];
    const float* enc_w2  = (const float*)d_in[7];
    const float* enc_b2  = (const float*)d_in[8];
    const float* enc_w3  = (const float*)d_in[9];
    const float* enc_b3  = (const float*)d_in[10];
    const float* skip_w  = (const float*)d_in[11];
    const float* skip_b  = (const float*)d_in[12];
    const float* gcn_w   = (const float*)d_in[13];
    const float* gcn_b   = (const float*)d_in[14];
    const float* ln_g    = (const float*)d_in[15];
    const float* ln_b    = (const float*)d_in[16];
    float* out = (float*)d_out;

    char* ws = (char*)d_ws;
    size_t o = 0;
    auto alloc = [&](size_t bytes) {
        char* p = ws + o;
        o += (bytes + 255) & ~(size_t)255;
        return p;
    };
    float*          hi     = (float*)alloc((size_t)N_NODES * HDIM * 4);
    unsigned short* xh     = (unsigned short*)alloc((size_t)N_NODES * HDIM * 2);
    unsigned short* xl     = (unsigned short*)alloc((size_t)N_NODES * HDIM * 2);
    unsigned short* wth    = (unsigned short*)alloc((size_t)NLAYERS * HDIM * HDIM * 2);
    unsigned short* wtl    = (unsigned short*)alloc((size_t)NLAYERS * HDIM * HDIM * 2);
    int*   degi    = (int*)alloc((size_t)N_NODES * 4);
    float* dis     = (float*)alloc((size_t)N_NODES * 4);
    int*   off     = (int*)alloc((size_t)(N_NODES + 1) * 4);
    int*   cursor  = (int*)alloc((size_t)N_NODES * 4);
    int*   csr_src = (int*)alloc((size_t)N_EDGES * 4);
    int*   ccnt    = (int*)alloc((size_t)NCLUST * 4);
    int*   coff    = (int*)alloc((size_t)(NCLUST + 1) * 4);
    int*   ccur    = (int*)alloc((size_t)NCLUST * 4);
    int*   cnodes  = (int*)alloc((size_t)N_NODES * 4);
    float* pooled  = (float*)alloc((size_t)NCLUST * HDIM * 4);
    float* colsq   = (float*)alloc((size_t)256 * 4);

    const int* esrc = edge_index;
    const int* edst = edge_index + N_EDGES;

    hipMemsetAsync(degi, 0, (size_t)N_NODES * 4, stream);
    hipMemsetAsync(cursor, 0, (size_t)N_NODES * 4, stream);
    hipMemsetAsync(ccnt, 0, (size_t)NCLUST * 4, stream);
    hipMemsetAsync(ccur, 0, (size_t)NCLUST * 4, stream);
    hipMemsetAsync(colsq, 0, (size_t)256 * 4, stream);

    encoder_kernel<<<N_NODES / 16, 256, 0, stream>>>(
        x_geo, id_index, id_emb, enc_w1, enc_b1, enc_w2, enc_b2, enc_w3, enc_b3,
        skip_w, skip_b, xh, xl);

    wtrans_kernel<<<dim3(8, NLAYERS), 256, 0, stream>>>(gcn_w, wth, wtl);

    count_kernel<<<N_EDGES / 256, 256, 0, stream>>>(edst, degi);
    dis_kernel<<<N_NODES / 256, 256, 0, stream>>>(degi, dis);
    scan_kernel<<<1, 1024, 0, stream>>>(degi, off);
    fill_kernel<<<N_EDGES / 256, 256, 0, stream>>>(esrc, edst, off, cursor, csr_src);

    ccount_kernel<<<N_NODES / 256, 256, 0, stream>>>(cluster, ccnt);
    cscan_kernel<<<1, 1024, 0, stream>>>(ccnt, coff);
    cfill_kernel<<<N_NODES / 256, 256, 0, stream>>>(cluster, coff, ccur, cnodes);

    for (int i = 0; i < NLAYERS; ++i) {
        mfma_gemm_kernel<<<N_NODES / 128, 512, 0, stream>>>(
            xh, xl, wth + (size_t)i * HDIM * HDIM, wtl + (size_t)i * HDIM * HDIM, hi);
        agg_ln_kernel<<<N_NODES / 4, 256, 0, stream>>>(
            hi, dis, off, csr_src, gcn_b + (size_t)i * HDIM,
            ln_g + (size_t)i * HDIM, ln_b + (size_t)i * HDIM, xh, xl, (i == 0) ? 1 : 0);
    }

    pool_csr_kernel<<<NCLUST / 4, 256, 0, stream>>>(xh, xl, coff, cnodes, pooled);
    colsq_kernel<<<NCLUST / 16, 256, 0, stream>>>(pooled, colsq);
    final_kernel<<<NCLUST * HDIM / 256, 256, 0, stream>>>(pooled, colsq, out);
}